// Round 3
// baseline (1927.132 us; speedup 1.0000x reference)
//
#include <hip/hip_runtime.h>
#include <cstdint>
#include <cstddef>

#define GLOBAL_AS __attribute__((address_space(1)))
#define LDS_AS    __attribute__((address_space(3)))

typedef __bf16 bf16;
typedef __bf16 bf16x8 __attribute__((ext_vector_type(8)));
typedef float  f32x4  __attribute__((ext_vector_type(4)));

__device__ __forceinline__ void gl_lds16(const void* g, void* l) {
  // 16B-per-lane async global->LDS; LDS dest = wave-uniform base + lane*16
  __builtin_amdgcn_global_load_lds((GLOBAL_AS void*)g, (LDS_AS void*)l, 16, 0, 0);
}

// ---------------- LayerNorm: fp32 (rows of 2048) -> bf16 ----------------
__global__ __launch_bounds__(256) void ln_kernel(const float* __restrict__ x,
                                                 const float* __restrict__ w,
                                                 const float* __restrict__ bias,
                                                 bf16* __restrict__ out) {
  const int row = blockIdx.x;
  const int tid = threadIdx.x;
  const float* xr = x + (size_t)row * 2048;
  f32x4 v0 = ((const f32x4*)xr)[tid * 2];
  f32x4 v1 = ((const f32x4*)xr)[tid * 2 + 1];
  float s = 0.f, ss = 0.f;
#pragma unroll
  for (int j = 0; j < 4; ++j) { s += v0[j]; ss += v0[j] * v0[j]; }
#pragma unroll
  for (int j = 0; j < 4; ++j) { s += v1[j]; ss += v1[j] * v1[j]; }
#pragma unroll
  for (int d = 1; d < 64; d <<= 1) { s += __shfl_xor(s, d); ss += __shfl_xor(ss, d); }
  __shared__ float red[8];
  const int wave = tid >> 6, lane = tid & 63;
  if (lane == 0) { red[wave * 2] = s; red[wave * 2 + 1] = ss; }
  __syncthreads();
  s  = red[0] + red[2] + red[4] + red[6];
  ss = red[1] + red[3] + red[5] + red[7];
  const float mean = s * (1.f / 2048.f);
  const float var  = ss * (1.f / 2048.f) - mean * mean;  // biased, matches jnp var
  const float rstd = rsqrtf(var + 1e-5f);
  const int col = tid * 8;
  bf16x8 o;
#pragma unroll
  for (int j = 0; j < 4; ++j) o[j]     = (bf16)((v0[j] - mean) * rstd * w[col + j]     + bias[col + j]);
#pragma unroll
  for (int j = 0; j < 4; ++j) o[4 + j] = (bf16)((v1[j] - mean) * rstd * w[col + 4 + j] + bias[col + 4 + j]);
  *(bf16x8*)(out + (size_t)row * 2048 + col) = o;
}

// -------- Dequant + LoRA fold: W[o,i] = qw*sc[o]+zp[o]+2*(B@A)[o,i] --------
__global__ __launch_bounds__(256) void dequant_kernel(const int* __restrict__ qw,
    const float* __restrict__ sc, const float* __restrict__ zp,
    const float* __restrict__ A, const float* __restrict__ Bm,
    bf16* __restrict__ W, int out_f, int in_f) {
  const int per_row = in_f >> 3;
  const int idx = blockIdx.x * 256 + threadIdx.x;   // grid sized exactly out_f*in_f/8/256
  const int o  = idx / per_row;
  const int i0 = (idx - o * per_row) << 3;
  const float s = sc[o], z = zp[o];
  float bl[16];
#pragma unroll
  for (int r = 0; r < 16; ++r) bl[r] = Bm[o * 16 + r];
  float acc[8] = {0.f, 0.f, 0.f, 0.f, 0.f, 0.f, 0.f, 0.f};
#pragma unroll
  for (int r = 0; r < 16; ++r) {
    const f32x4* ap = (const f32x4*)(A + (size_t)r * in_f + i0);
    f32x4 a0 = ap[0], a1 = ap[1];
#pragma unroll
    for (int j = 0; j < 4; ++j) { acc[j] += bl[r] * a0[j]; acc[4 + j] += bl[r] * a1[j]; }
  }
  const int* qp = qw + (size_t)o * in_f + i0;
  bf16x8 w8;
#pragma unroll
  for (int j = 0; j < 8; ++j) w8[j] = (bf16)((float)qp[j] * s + z + 2.f * acc[j]);
  *(bf16x8*)(W + (size_t)o * in_f + i0) = w8;
}

// -------- bf16 GEMM: C[M,N] = A[M,K] @ B[N,K]^T, 128xTN tile, BK=64 --------
// MODE 0: Cb = bf16(acc)                       (ldc = N)
// MODE 1: Cf = res + acc (fp32 residual add)
// MODE 2: Cb = silu(gate)*acc (gate may alias Cb)
// MODE 3: qkv epilogue: cols<4096 -> Cqk (ldc=4096); cols>=4096 -> V^T scatter to vt
// MODE 4: atomicAdd(Cf, acc)  (split-K over gridDim.z)
template <int MODE, int TN>
__global__ __launch_bounds__(256) void gemm_kernel(const bf16* __restrict__ A,
    const bf16* __restrict__ B, bf16* __restrict__ Cb, float* __restrict__ Cf,
    const float* __restrict__ res, const bf16* __restrict__ gate, bf16* __restrict__ vt,
    int M, int N, int K, int ldc) {
  constexpr int JN = TN / 32;       // 16-col tiles per wave
  constexpr int NB = TN / 32;       // B staging instrs per wave (8 rows each)
  const int n0 = blockIdx.x * TN;
  const int m0 = blockIdx.y * 128;
  const int tid = threadIdx.x;
  const int wave = tid >> 6, lane = tid & 63;
  const int lcol = lane & 15, lrow = lane >> 4;
  const int wm = (wave >> 1) * 64, wn = (wave & 1) * (JN * 16);
  __shared__ bf16 As[128 * 64];
  __shared__ bf16 Bs[TN * 64];
  f32x4 acc[4][JN] = {};
  const int klen = K / gridDim.z;
  const int k0 = blockIdx.z * klen;
  const bf16* Ag = A + (size_t)(m0 + wave * 32 + (lane >> 3)) * K + (lane & 7) * 8;
  const bf16* Bg = B + (size_t)(n0 + wave * (TN / 4) + (lane >> 3)) * K + (lane & 7) * 8;
  for (int kt = k0; kt < k0 + klen; kt += 64) {
#pragma unroll
    for (int r8 = 0; r8 < 4; ++r8)
      gl_lds16(Ag + (size_t)r8 * 8 * K + kt, As + (wave * 32 + r8 * 8) * 64);
#pragma unroll
    for (int r8 = 0; r8 < NB; ++r8)
      gl_lds16(Bg + (size_t)r8 * 8 * K + kt, Bs + (wave * (TN / 4) + r8 * 8) * 64);
    __syncthreads();
#pragma unroll
    for (int ks = 0; ks < 2; ++ks) {
      bf16x8 af[4], bfr[JN];
#pragma unroll
      for (int i = 0; i < 4; ++i)  af[i]  = *(const bf16x8*)(As + (wm + i * 16 + lcol) * 64 + ks * 32 + lrow * 8);
#pragma unroll
      for (int j = 0; j < JN; ++j) bfr[j] = *(const bf16x8*)(Bs + (wn + j * 16 + lcol) * 64 + ks * 32 + lrow * 8);
#pragma unroll
      for (int i = 0; i < 4; ++i)
#pragma unroll
        for (int j = 0; j < JN; ++j)
          acc[i][j] = __builtin_amdgcn_mfma_f32_16x16x32_bf16(af[i], bfr[j], acc[i][j], 0, 0, 0);
    }
    __syncthreads();
  }
#pragma unroll
  for (int i = 0; i < 4; ++i)
#pragma unroll
    for (int j = 0; j < JN; ++j)
#pragma unroll
      for (int r = 0; r < 4; ++r) {
        const int row = m0 + wm + i * 16 + lrow * 4 + r;   // C/D: row = quad*4+reg
        const int col = n0 + wn + j * 16 + lcol;           //      col = lane&15
        const float v = acc[i][j][r];
        if (MODE == 0) {
          Cb[(size_t)row * ldc + col] = (bf16)v;
        } else if (MODE == 1) {
          const size_t idx = (size_t)row * ldc + col;
          Cf[idx] = res[idx] + v;
        } else if (MODE == 2) {
          const size_t idx = (size_t)row * ldc + col;
          const float g = (float)gate[idx];
          Cb[idx] = (bf16)((g / (1.f + __expf(-g))) * v);
        } else if (MODE == 3) {
          if (n0 < 4096) {
            Cb[(size_t)row * 4096 + col] = (bf16)v;        // q|k packed, ld 4096
          } else {
            const int c2 = col - 4096;                     // v -> V^T[(b*16+h)*128+d][s]
            const int hh = c2 >> 7, dd = c2 & 127;
            const int bb = row >> 11, sS = row & 2047;
            vt[(size_t)((((bb << 4) | hh) << 7) | dd) * 2048 + sS] = (bf16)v;
          }
        } else {
          atomicAdd(&Cf[(size_t)row * ldc + col], v);
        }
      }
}

// -------- Flash attention, barrier-free: K/V^T frags straight from global --------
// Cqk: [4096][4096] (q|k per row), VtG: [(b*16+h)*128+d][2048], obuf: [4096][2048]
__global__ __launch_bounds__(256) void attn_kernel(const bf16* __restrict__ Cqk,
                                                   const bf16* __restrict__ VtG,
                                                   bf16* __restrict__ obuf) {
  const int qt = blockIdx.x, h = blockIdx.y, b = blockIdx.z;
  const int tid = threadIdx.x, wave = tid >> 6, lane = tid & 63;
  const int lcol = lane & 15, lrow = lane >> 4;
  const int qrow0 = b * 2048 + qt * 64 + wave * 16;   // wave's 16 q-rows
  __shared__ bf16 Ps[4][16 * 68];                     // stride 68: write-conflict-free
  bf16* ps = Ps[wave];
  // Q fragments (A-layout) once
  bf16x8 qf[4];
#pragma unroll
  for (int dk = 0; dk < 4; ++dk)
    qf[dk] = *(const bf16x8*)(Cqk + (size_t)(qrow0 + lcol) * 4096 + h * 128 + dk * 32 + lrow * 8);
  f32x4 of[8] = {};
  float m_run[4], l_run[4];
#pragma unroll
  for (int r = 0; r < 4; ++r) { m_run[r] = -1e30f; l_run[r] = 0.f; }
  const float SCL2 = 0.12751874972f;  // 1/sqrt(128) * log2(e); exp2-domain softmax
  const bf16* Kbase = Cqk + 2048 + h * 128 + lrow * 8;
  const bf16* Vbase = VtG + (size_t)((b * 16 + h) * 128) * 2048;

  for (int kt = 0; kt < 2048; kt += 64) {
    // S = Q @ K^T : B-frags loaded straight from global (L2-resident)
    f32x4 sacc[4] = {};
#pragma unroll
    for (int jb = 0; jb < 4; ++jb) {
      const bf16* kr = Kbase + (size_t)(b * 2048 + kt + jb * 16 + lcol) * 4096;
      bf16x8 k0 = *(const bf16x8*)(kr);
      bf16x8 k1 = *(const bf16x8*)(kr + 32);
      bf16x8 k2 = *(const bf16x8*)(kr + 64);
      bf16x8 k3 = *(const bf16x8*)(kr + 96);
      sacc[jb] = __builtin_amdgcn_mfma_f32_16x16x32_bf16(qf[0], k0, sacc[jb], 0, 0, 0);
      sacc[jb] = __builtin_amdgcn_mfma_f32_16x16x32_bf16(qf[1], k1, sacc[jb], 0, 0, 0);
      sacc[jb] = __builtin_amdgcn_mfma_f32_16x16x32_bf16(qf[2], k2, sacc[jb], 0, 0, 0);
      sacc[jb] = __builtin_amdgcn_mfma_f32_16x16x32_bf16(qf[3], k3, sacc[jb], 0, 0, 0);
    }
    // online softmax; row r of quad lives in lanes sharing lrow -> reduce over lcol
    float z[4][4], mx[4], rs[4];
#pragma unroll
    for (int jb = 0; jb < 4; ++jb)
#pragma unroll
      for (int r = 0; r < 4; ++r) z[jb][r] = sacc[jb][r] * SCL2;
#pragma unroll
    for (int r = 0; r < 4; ++r)
      mx[r] = fmaxf(fmaxf(z[0][r], z[1][r]), fmaxf(z[2][r], z[3][r]));
#pragma unroll
    for (int d = 1; d < 16; d <<= 1)
#pragma unroll
      for (int r = 0; r < 4; ++r) mx[r] = fmaxf(mx[r], __shfl_xor(mx[r], d));
#pragma unroll
    for (int r = 0; r < 4; ++r) {
      const float mn = fmaxf(m_run[r], mx[r]);
      const float alpha = __builtin_amdgcn_exp2f(m_run[r] - mn);
      m_run[r] = mn;
      float srow = 0.f;
#pragma unroll
      for (int jb = 0; jb < 4; ++jb) {
        const float p = __builtin_amdgcn_exp2f(z[jb][r] - mn);
        z[jb][r] = p; srow += p;
      }
      rs[r] = srow;
      l_run[r] *= alpha;
#pragma unroll
      for (int db = 0; db < 8; ++db) of[db][r] *= alpha;
    }
#pragma unroll
    for (int d = 1; d < 16; d <<= 1)
#pragma unroll
      for (int r = 0; r < 4; ++r) rs[r] += __shfl_xor(rs[r], d);
#pragma unroll
    for (int r = 0; r < 4; ++r) l_run[r] += rs[r];
    // P: C-layout -> per-wave LDS -> A-layout (same-wave, no barrier)
#pragma unroll
    for (int jb = 0; jb < 4; ++jb)
#pragma unroll
      for (int r = 0; r < 4; ++r)
        ps[(lrow * 4 + r) * 68 + jb * 16 + lcol] = (bf16)z[jb][r];
    // O += P @ V : V^T B-frags straight from global
#pragma unroll
    for (int ss = 0; ss < 2; ++ss) {
      bf16x8 af = *(const bf16x8*)(ps + lcol * 68 + ss * 32 + lrow * 8);
#pragma unroll
      for (int db = 0; db < 8; ++db) {
        bf16x8 vf = *(const bf16x8*)(Vbase + (size_t)(db * 16 + lcol) * 2048 + kt + ss * 32 + lrow * 8);
        of[db] = __builtin_amdgcn_mfma_f32_16x16x32_bf16(af, vf, of[db], 0, 0, 0);
      }
    }
  }
#pragma unroll
  for (int r = 0; r < 4; ++r) {
    const float inv = 1.f / l_run[r];
    const size_t rb = (size_t)(qrow0 + lrow * 4 + r) * 2048 + h * 128;
#pragma unroll
    for (int db = 0; db < 8; ++db)
      obuf[rb + db * 16 + lcol] = (bf16)(of[db][r] * inv);
  }
}

extern "C" void kernel_launch(void* const* d_in, const int* in_sizes, int n_in,
                              void* d_out, int out_size, void* d_ws, size_t ws_size,
                              hipStream_t stream) {
  (void)in_sizes; (void)n_in; (void)out_size; (void)ws_size;
  const int*   q_qw = (const int*)d_in[0];   const float* q_sc = (const float*)d_in[1];
  const float* q_zp = (const float*)d_in[2]; const float* q_A  = (const float*)d_in[3];
  const float* q_B  = (const float*)d_in[4];
  const int*   k_qw = (const int*)d_in[5];   const float* k_sc = (const float*)d_in[6];
  const float* k_zp = (const float*)d_in[7]; const float* k_A  = (const float*)d_in[8];
  const float* k_B  = (const float*)d_in[9];
  const int*   v_qw = (const int*)d_in[10];  const float* v_sc = (const float*)d_in[11];
  const float* v_zp = (const float*)d_in[12];const float* v_A  = (const float*)d_in[13];
  const float* v_B  = (const float*)d_in[14];
  const int*   o_qw = (const int*)d_in[15];  const float* o_sc = (const float*)d_in[16];
  const float* o_zp = (const float*)d_in[17];const float* o_A  = (const float*)d_in[18];
  const float* o_B  = (const float*)d_in[19];
  const int*   g_qw = (const int*)d_in[20];  const float* g_sc = (const float*)d_in[21];
  const float* g_zp = (const float*)d_in[22];const float* g_A  = (const float*)d_in[23];
  const float* g_B  = (const float*)d_in[24];
  const int*   u_qw = (const int*)d_in[25];  const float* u_sc = (const float*)d_in[26];
  const float* u_zp = (const float*)d_in[27];const float* u_A  = (const float*)d_in[28];
  const float* u_B  = (const float*)d_in[29];
  const int*   d_qw = (const int*)d_in[30];  const float* d_sc = (const float*)d_in[31];
  const float* d_zp = (const float*)d_in[32];const float* d_A  = (const float*)d_in[33];
  const float* d_B  = (const float*)d_in[34];
  const float* x    = (const float*)d_in[35];
  const float* ln1w = (const float*)d_in[36];const float* ln1b = (const float*)d_in[37];
  const float* ln2w = (const float*)d_in[38];const float* ln2b = (const float*)d_in[39];

  // workspace arena — peak 112 MiB (W 32 + h 16 + C 64); x1 lives in d_out (fp32)
  char* ws = (char*)d_ws;
  bf16* W = (bf16*)ws;                                    // 32 MiB dequant scratch
  bf16* h = (bf16*)(ws + (size_t)32 * 1024 * 1024);       // 16 MiB LN out
  bf16* C = (bf16*)(ws + (size_t)48 * 1024 * 1024);       // 64 MiB
  bf16* Cqk = C;                                          // [4096][4096] q|k (32 MiB)
  bf16* VtG = C + (size_t)4096 * 4096;                    // [2*16*128][2048] (16 MiB)
  bf16* obuf = VtG + (size_t)2 * 16 * 128 * 2048;         // [4096][2048] (16 MiB)
  float* x1  = (float*)d_out;
  float* out = (float*)d_out;

  // 1. h = LN1(x)
  ln_kernel<<<4096, 256, 0, stream>>>(x, ln1w, ln1b, h);
  // 2. dequant W_q|W_k|W_v (6144x2048)
  dequant_kernel<<<2048, 256, 0, stream>>>(q_qw, q_sc, q_zp, q_A, q_B, W, 2048, 2048);
  dequant_kernel<<<2048, 256, 0, stream>>>(k_qw, k_sc, k_zp, k_A, k_B, W + (size_t)2048 * 2048, 2048, 2048);
  dequant_kernel<<<2048, 256, 0, stream>>>(v_qw, v_sc, v_zp, v_A, v_B, W + (size_t)4096 * 2048, 2048, 2048);
  // 3. qkv GEMM: q|k -> Cqk, v -> VtG (transposed scatter epilogue)
  gemm_kernel<3, 128><<<dim3(48, 32, 1), 256, 0, stream>>>(h, W, Cqk, nullptr, nullptr, nullptr, VtG, 4096, 6144, 2048, 4096);
  // 4. attention (barrier-free)
  attn_kernel<<<dim3(32, 16, 2), 256, 0, stream>>>(Cqk, VtG, obuf);
  // 5-6. x1 = x + o @ W_o^T  (128x64 tiles -> 1024 blocks)
  dequant_kernel<<<2048, 256, 0, stream>>>(o_qw, o_sc, o_zp, o_A, o_B, W, 2048, 2048);
  gemm_kernel<1, 64><<<dim3(32, 32, 1), 256, 0, stream>>>(obuf, W, nullptr, x1, x, nullptr, nullptr, 4096, 2048, 2048, 2048);
  // 7. h2 = LN2(x1)
  ln_kernel<<<4096, 256, 0, stream>>>(x1, ln2w, ln2b, h);
  // 8-9. g = h2 @ W_g^T  (C reused as 4096x8192)
  dequant_kernel<<<8192, 256, 0, stream>>>(g_qw, g_sc, g_zp, g_A, g_B, W, 8192, 2048);
  gemm_kernel<0, 128><<<dim3(64, 32, 1), 256, 0, stream>>>(h, W, C, nullptr, nullptr, nullptr, nullptr, 4096, 8192, 2048, 8192);
  // 10-11. ff = silu(g) * (h2 @ W_u^T), in-place over C
  dequant_kernel<<<8192, 256, 0, stream>>>(u_qw, u_sc, u_zp, u_A, u_B, W, 8192, 2048);
  gemm_kernel<2, 128><<<dim3(64, 32, 1), 256, 0, stream>>>(h, W, C, nullptr, nullptr, C, nullptr, 4096, 8192, 2048, 8192);
  // 12-13. out = x1 + ff @ W_d^T  (split-K=4, atomic accumulate into x1-initialized out)
  dequant_kernel<<<8192, 256, 0, stream>>>(d_qw, d_sc, d_zp, d_A, d_B, W, 2048, 8192);
  gemm_kernel<4, 128><<<dim3(16, 32, 4), 256, 0, stream>>>(C, W, nullptr, out, nullptr, nullptr, nullptr, 4096, 2048, 8192, 2048);
}

// Round 4
// 1548.312 us; speedup vs baseline: 1.2447x; 1.2447x over previous
//
#include <hip/hip_runtime.h>
#include <cstdint>
#include <cstddef>

#define GLOBAL_AS __attribute__((address_space(1)))
#define LDS_AS    __attribute__((address_space(3)))

typedef __bf16 bf16;
typedef __bf16 bf16x4 __attribute__((ext_vector_type(4)));
typedef __bf16 bf16x8 __attribute__((ext_vector_type(8)));
typedef float  f32x4  __attribute__((ext_vector_type(4)));

__device__ __forceinline__ void gl_lds16(const void* g, void* l) {
  // 16B-per-lane async global->LDS; LDS dest = wave-uniform base + lane*16
  __builtin_amdgcn_global_load_lds((GLOBAL_AS void*)g, (LDS_AS void*)l, 16, 0, 0);
}

// ---------------- LayerNorm: fp32 (rows of 2048) -> bf16 ----------------
__global__ __launch_bounds__(256) void ln_kernel(const float* __restrict__ x,
                                                 const float* __restrict__ w,
                                                 const float* __restrict__ bias,
                                                 bf16* __restrict__ out) {
  const int row = blockIdx.x;
  const int tid = threadIdx.x;
  const float* xr = x + (size_t)row * 2048;
  f32x4 v0 = ((const f32x4*)xr)[tid * 2];
  f32x4 v1 = ((const f32x4*)xr)[tid * 2 + 1];
  float s = 0.f, ss = 0.f;
#pragma unroll
  for (int j = 0; j < 4; ++j) { s += v0[j]; ss += v0[j] * v0[j]; }
#pragma unroll
  for (int j = 0; j < 4; ++j) { s += v1[j]; ss += v1[j] * v1[j]; }
#pragma unroll
  for (int d = 1; d < 64; d <<= 1) { s += __shfl_xor(s, d); ss += __shfl_xor(ss, d); }
  __shared__ float red[8];
  const int wave = tid >> 6, lane = tid & 63;
  if (lane == 0) { red[wave * 2] = s; red[wave * 2 + 1] = ss; }
  __syncthreads();
  s  = red[0] + red[2] + red[4] + red[6];
  ss = red[1] + red[3] + red[5] + red[7];
  const float mean = s * (1.f / 2048.f);
  const float var  = ss * (1.f / 2048.f) - mean * mean;  // biased, matches jnp var
  const float rstd = rsqrtf(var + 1e-5f);
  const int col = tid * 8;
  bf16x8 o;
#pragma unroll
  for (int j = 0; j < 4; ++j) o[j]     = (bf16)((v0[j] - mean) * rstd * w[col + j]     + bias[col + j]);
#pragma unroll
  for (int j = 0; j < 4; ++j) o[4 + j] = (bf16)((v1[j] - mean) * rstd * w[col + 4 + j] + bias[col + 4 + j]);
  *(bf16x8*)(out + (size_t)row * 2048 + col) = o;
}

// -------- Dequant + LoRA fold: W[o,i] = qw*sc[o]+zp[o]+2*(B@A)[o,i] --------
__global__ __launch_bounds__(256) void dequant_kernel(const int* __restrict__ qw,
    const float* __restrict__ sc, const float* __restrict__ zp,
    const float* __restrict__ A, const float* __restrict__ Bm,
    bf16* __restrict__ W, int out_f, int in_f) {
  const int per_row = in_f >> 3;
  const int idx = blockIdx.x * 256 + threadIdx.x;   // grid sized exactly out_f*in_f/8/256
  const int o  = idx / per_row;
  const int i0 = (idx - o * per_row) << 3;
  const float s = sc[o], z = zp[o];
  float bl[16];
#pragma unroll
  for (int r = 0; r < 16; ++r) bl[r] = Bm[o * 16 + r];
  float acc[8] = {0.f, 0.f, 0.f, 0.f, 0.f, 0.f, 0.f, 0.f};
#pragma unroll
  for (int r = 0; r < 16; ++r) {
    const f32x4* ap = (const f32x4*)(A + (size_t)r * in_f + i0);
    f32x4 a0 = ap[0], a1 = ap[1];
#pragma unroll
    for (int j = 0; j < 4; ++j) { acc[j] += bl[r] * a0[j]; acc[4 + j] += bl[r] * a1[j]; }
  }
  const int* qp = qw + (size_t)o * in_f + i0;
  bf16x8 w8;
#pragma unroll
  for (int j = 0; j < 8; ++j) w8[j] = (bf16)((float)qp[j] * s + z + 2.f * acc[j]);
  *(bf16x8*)(W + (size_t)o * in_f + i0) = w8;
}

// -------- bf16 GEMM: C[M,N] = A[M,K] @ B[N,K]^T, 128xTN tile, BK=64 --------
// MODE 0: Cb = bf16(acc)                       (ldc = N)
// MODE 1: Cf = res + acc (fp32 residual add; res may alias Cf)
// MODE 2: Cb = silu(gate)*acc (gate may alias Cb)
// MODE 3: qkv epilogue: cols<4096 -> Cb=Cqk (ldc=4096); cols>=4096 -> V^T packed 8B store to vt
template <int MODE, int TN>
__global__ __launch_bounds__(256) void gemm_kernel(const bf16* __restrict__ A,
    const bf16* __restrict__ B, bf16* __restrict__ Cb, float* __restrict__ Cf,
    const float* __restrict__ res, const bf16* __restrict__ gate, bf16* __restrict__ vt,
    int M, int N, int K, int ldc) {
  constexpr int JN = TN / 32;       // 16-col tiles per wave
  constexpr int NB = TN / 32;       // B staging instrs per wave (8 rows each)
  const int n0 = blockIdx.x * TN;
  const int m0 = blockIdx.y * 128;
  const int tid = threadIdx.x;
  const int wave = tid >> 6, lane = tid & 63;
  const int lcol = lane & 15, lrow = lane >> 4;
  const int wm = (wave >> 1) * 64, wn = (wave & 1) * (JN * 16);
  __shared__ bf16 As[128 * 64];
  __shared__ bf16 Bs[TN * 64];
  f32x4 acc[4][JN] = {};
  const bf16* Ag = A + (size_t)(m0 + wave * 32 + (lane >> 3)) * K + (lane & 7) * 8;
  const bf16* Bg = B + (size_t)(n0 + wave * (TN / 4) + (lane >> 3)) * K + (lane & 7) * 8;
  for (int kt = 0; kt < K; kt += 64) {
#pragma unroll
    for (int r8 = 0; r8 < 4; ++r8)
      gl_lds16(Ag + (size_t)r8 * 8 * K + kt, As + (wave * 32 + r8 * 8) * 64);
#pragma unroll
    for (int r8 = 0; r8 < NB; ++r8)
      gl_lds16(Bg + (size_t)r8 * 8 * K + kt, Bs + (wave * (TN / 4) + r8 * 8) * 64);
    __syncthreads();
#pragma unroll
    for (int ks = 0; ks < 2; ++ks) {
      bf16x8 af[4], bfr[JN];
#pragma unroll
      for (int i = 0; i < 4; ++i)  af[i]  = *(const bf16x8*)(As + (wm + i * 16 + lcol) * 64 + ks * 32 + lrow * 8);
#pragma unroll
      for (int j = 0; j < JN; ++j) bfr[j] = *(const bf16x8*)(Bs + (wn + j * 16 + lcol) * 64 + ks * 32 + lrow * 8);
#pragma unroll
      for (int i = 0; i < 4; ++i)
#pragma unroll
        for (int j = 0; j < JN; ++j)
          acc[i][j] = __builtin_amdgcn_mfma_f32_16x16x32_bf16(af[i], bfr[j], acc[i][j], 0, 0, 0);
    }
    __syncthreads();
  }
#pragma unroll
  for (int i = 0; i < 4; ++i)
#pragma unroll
    for (int j = 0; j < JN; ++j) {
      const int row0 = m0 + wm + i * 16 + lrow * 4;      // C/D: row = quad*4+reg
      const int col  = n0 + wn + j * 16 + lcol;          //      col = lane&15
      if (MODE == 3 && n0 >= 4096) {
        // v -> V^T[(b*16+h)*128+d][s]; 4 consecutive s per lane -> packed 8B store
        const int c2 = col - 4096;
        bf16x4 v4;
#pragma unroll
        for (int r = 0; r < 4; ++r) v4[r] = (bf16)acc[i][j][r];
        *(bf16x4*)(vt + (size_t)(((row0 >> 11) * 16 + (c2 >> 7)) * 128 + (c2 & 127)) * 2048
                      + (row0 & 2047)) = v4;
      } else {
#pragma unroll
        for (int r = 0; r < 4; ++r) {
          const int row = row0 + r;
          const float v = acc[i][j][r];
          const size_t idx = (size_t)row * ldc + col;
          if (MODE == 0)      Cb[idx] = (bf16)v;
          else if (MODE == 1) Cf[idx] = res[idx] + v;
          else if (MODE == 2) {
            const float g = (float)gate[idx];
            Cb[idx] = (bf16)((g / (1.f + __expf(-g))) * v);
          } else Cb[idx] = (bf16)v;  // MODE 3 q|k part (ldc=4096)
        }
      }
    }
}

// -------- Flash attention: Cqk [4096][4096] (q|k), VtG [(b*16+h)*128+d][2048] --------
// 128 q-rows/block (32/wave). K & V^T staged via async global->LDS with XOR-swizzled
// 16B chunks (slot = c ^ (row & mask)) so fragment ds_read_b128 spread over all banks.
__global__ __launch_bounds__(256) void attn_kernel(const bf16* __restrict__ Cqk,
                                                   const bf16* __restrict__ VtG,
                                                   bf16* __restrict__ obuf) {
  const int qt = blockIdx.x, h = blockIdx.y, b = blockIdx.z;
  const int tid = threadIdx.x, wave = tid >> 6, lane = tid & 63;
  const int lcol = lane & 15, lrow = lane >> 4;
  const int base_m = b * 2048 + qt * 128;
  __shared__ bf16 Ks[64 * 128];     // [s][d], swizzled 16B chunks (mask 15)
  __shared__ bf16 Vt[128 * 64];     // [d][s], swizzled 16B chunks (mask 7)
  __shared__ bf16 Ps[4][32 * 72];   // per-wave P, stride 72
  bf16* ps = Ps[wave];
  // Q fragments (A-layout) once, from global
  bf16x8 qf[2][4];
#pragma unroll
  for (int i = 0; i < 2; ++i)
#pragma unroll
    for (int dk = 0; dk < 4; ++dk)
      qf[i][dk] = *(const bf16x8*)(Cqk + (size_t)(base_m + wave * 32 + i * 16 + lcol) * 4096
                                   + h * 128 + dk * 32 + lrow * 8);
  f32x4 of[2][8] = {};
  float m_run[2][4], l_run[2][4];
#pragma unroll
  for (int i = 0; i < 2; ++i)
#pragma unroll
    for (int r = 0; r < 4; ++r) { m_run[i][r] = -1e30f; l_run[i][r] = 0.f; }
  const float SCL2 = 0.12751874972f;  // (1/sqrt(128)) * log2(e); exp2-domain softmax
  const int vswz = (lane & 7) ^ (lane >> 3);   // V staging chunk permutation (constant)

  for (int kt = 0; kt < 2048; kt += 64) {
    // stage K tile: wave covers s in [wave*16, wave*16+16), 4 rows (256B) per instr
#pragma unroll
    for (int r4 = 0; r4 < 4; ++r4) {
      const int s_low = r4 * 4 + lrow;                   // s & 15
      gl_lds16(Cqk + (size_t)(b * 2048 + kt + wave * 16 + s_low) * 4096 + 2048 + h * 128
                   + (lcol ^ s_low) * 8,
               Ks + (wave * 16 + r4 * 4) * 128);
    }
    // stage V^T tile: wave covers d in [wave*32, wave*32+32), 8 rows (128B) per instr
#pragma unroll
    for (int r8 = 0; r8 < 4; ++r8)
      gl_lds16(VtG + (size_t)((b * 16 + h) * 128 + wave * 32 + r8 * 8 + (lane >> 3)) * 2048
                   + kt + vswz * 8,
               Vt + (wave * 32 + r8 * 8) * 64);
    __syncthreads();

    // S = Q @ K^T  (kf slot = (4dk+lrow) ^ lcol)
    f32x4 sacc[2][4] = {};
#pragma unroll
    for (int jb = 0; jb < 4; ++jb) {
      bf16x8 kf[4];
#pragma unroll
      for (int dk = 0; dk < 4; ++dk)
        kf[dk] = *(const bf16x8*)(Ks + (jb * 16 + lcol) * 128 + ((dk * 4 + lrow) ^ lcol) * 8);
#pragma unroll
      for (int i = 0; i < 2; ++i)
#pragma unroll
        for (int dk = 0; dk < 4; ++dk)
          sacc[i][jb] = __builtin_amdgcn_mfma_f32_16x16x32_bf16(qf[i][dk], kf[dk], sacc[i][jb], 0, 0, 0);
    }

    // online softmax; row = lrow*4+r, cols over (jb, lcol); reduce over 16 lcol lanes
#pragma unroll
    for (int i = 0; i < 2; ++i) {
      float z[4][4], mx[4];
#pragma unroll
      for (int jb = 0; jb < 4; ++jb)
#pragma unroll
        for (int r = 0; r < 4; ++r) z[jb][r] = sacc[i][jb][r] * SCL2;
#pragma unroll
      for (int r = 0; r < 4; ++r)
        mx[r] = fmaxf(fmaxf(z[0][r], z[1][r]), fmaxf(z[2][r], z[3][r]));
#pragma unroll
      for (int d = 1; d < 16; d <<= 1)
#pragma unroll
        for (int r = 0; r < 4; ++r) mx[r] = fmaxf(mx[r], __shfl_xor(mx[r], d));
#pragma unroll
      for (int r = 0; r < 4; ++r) {
        const float mn = fmaxf(m_run[i][r], mx[r]);
        const float alpha = __builtin_amdgcn_exp2f(m_run[i][r] - mn);
        m_run[i][r] = mn;
        float srow = 0.f;
#pragma unroll
        for (int jb = 0; jb < 4; ++jb) {
          const float p = __builtin_amdgcn_exp2f(z[jb][r] - mn);
          z[jb][r] = p; srow += p;
        }
        l_run[i][r] = l_run[i][r] * alpha + srow;   // per-lane partial; reduce at end
#pragma unroll
        for (int db = 0; db < 8; ++db) of[i][db][r] *= alpha;
      }
      // P: C-layout regs -> per-wave LDS (no barrier; same-wave lgkmcnt ordering)
#pragma unroll
      for (int jb = 0; jb < 4; ++jb)
#pragma unroll
        for (int r = 0; r < 4; ++r)
          ps[(i * 16 + lrow * 4 + r) * 72 + jb * 16 + lcol] = (bf16)z[jb][r];
    }

    // O += P @ V  (vf slot = (4ss+lrow) ^ (lcol&7))
#pragma unroll
    for (int ss = 0; ss < 2; ++ss) {
      bf16x8 a0 = *(const bf16x8*)(ps + (0 * 16 + lcol) * 72 + ss * 32 + lrow * 8);
      bf16x8 a1 = *(const bf16x8*)(ps + (1 * 16 + lcol) * 72 + ss * 32 + lrow * 8);
#pragma unroll
      for (int db = 0; db < 8; ++db) {
        bf16x8 vf = *(const bf16x8*)(Vt + (db * 16 + lcol) * 64 + ((ss * 4 + lrow) ^ (lcol & 7)) * 8);
        of[0][db] = __builtin_amdgcn_mfma_f32_16x16x32_bf16(a0, vf, of[0][db], 0, 0, 0);
        of[1][db] = __builtin_amdgcn_mfma_f32_16x16x32_bf16(a1, vf, of[1][db], 0, 0, 0);
      }
    }
    __syncthreads();
  }
  // final: reduce per-lane l partials over the 16 lcol lanes, normalize, store
#pragma unroll
  for (int i = 0; i < 2; ++i)
#pragma unroll
    for (int r = 0; r < 4; ++r) {
      float l = l_run[i][r];
#pragma unroll
      for (int d = 1; d < 16; d <<= 1) l += __shfl_xor(l, d);
      const float inv = 1.f / l;
      const size_t rb = (size_t)(base_m + wave * 32 + i * 16 + lrow * 4 + r) * 2048 + h * 128;
#pragma unroll
      for (int db = 0; db < 8; ++db)
        obuf[rb + db * 16 + lcol] = (bf16)(of[i][db][r] * inv);
    }
}

extern "C" void kernel_launch(void* const* d_in, const int* in_sizes, int n_in,
                              void* d_out, int out_size, void* d_ws, size_t ws_size,
                              hipStream_t stream) {
  (void)in_sizes; (void)n_in; (void)out_size; (void)ws_size;
  const int*   q_qw = (const int*)d_in[0];   const float* q_sc = (const float*)d_in[1];
  const float* q_zp = (const float*)d_in[2]; const float* q_A  = (const float*)d_in[3];
  const float* q_B  = (const float*)d_in[4];
  const int*   k_qw = (const int*)d_in[5];   const float* k_sc = (const float*)d_in[6];
  const float* k_zp = (const float*)d_in[7]; const float* k_A  = (const float*)d_in[8];
  const float* k_B  = (const float*)d_in[9];
  const int*   v_qw = (const int*)d_in[10];  const float* v_sc = (const float*)d_in[11];
  const float* v_zp = (const float*)d_in[12];const float* v_A  = (const float*)d_in[13];
  const float* v_B  = (const float*)d_in[14];
  const int*   o_qw = (const int*)d_in[15];  const float* o_sc = (const float*)d_in[16];
  const float* o_zp = (const float*)d_in[17];const float* o_A  = (const float*)d_in[18];
  const float* o_B  = (const float*)d_in[19];
  const int*   g_qw = (const int*)d_in[20];  const float* g_sc = (const float*)d_in[21];
  const float* g_zp = (const float*)d_in[22];const float* g_A  = (const float*)d_in[23];
  const float* g_B  = (const float*)d_in[24];
  const int*   u_qw = (const int*)d_in[25];  const float* u_sc = (const float*)d_in[26];
  const float* u_zp = (const float*)d_in[27];const float* u_A  = (const float*)d_in[28];
  const float* u_B  = (const float*)d_in[29];
  const int*   d_qw = (const int*)d_in[30];  const float* d_sc = (const float*)d_in[31];
  const float* d_zp = (const float*)d_in[32];const float* d_A  = (const float*)d_in[33];
  const float* d_B  = (const float*)d_in[34];
  const float* x    = (const float*)d_in[35];
  const float* ln1w = (const float*)d_in[36];const float* ln1b = (const float*)d_in[37];
  const float* ln2w = (const float*)d_in[38];const float* ln2b = (const float*)d_in[39];

  // workspace arena — peak 112 MiB (W 32 + h 16 + C 64); x1 lives in d_out (fp32)
  char* ws = (char*)d_ws;
  bf16* W = (bf16*)ws;                                    // 32 MiB dequant scratch
  bf16* h = (bf16*)(ws + (size_t)32 * 1024 * 1024);       // 16 MiB LN out
  bf16* C = (bf16*)(ws + (size_t)48 * 1024 * 1024);       // 64 MiB
  bf16* Cqk = C;                                          // [4096][4096] q|k (32 MiB)
  bf16* VtG = C + (size_t)4096 * 4096;                    // [2*16*128][2048] (16 MiB)
  bf16* obuf = VtG + (size_t)2 * 16 * 128 * 2048;         // [4096][2048] (16 MiB)
  float* x1  = (float*)d_out;
  float* out = (float*)d_out;

  // 1. h = LN1(x)
  ln_kernel<<<4096, 256, 0, stream>>>(x, ln1w, ln1b, h);
  // 2. dequant W_q|W_k|W_v (6144x2048)
  dequant_kernel<<<2048, 256, 0, stream>>>(q_qw, q_sc, q_zp, q_A, q_B, W, 2048, 2048);
  dequant_kernel<<<2048, 256, 0, stream>>>(k_qw, k_sc, k_zp, k_A, k_B, W + (size_t)2048 * 2048, 2048, 2048);
  dequant_kernel<<<2048, 256, 0, stream>>>(v_qw, v_sc, v_zp, v_A, v_B, W + (size_t)4096 * 2048, 2048, 2048);
  // 3. qkv GEMM: q|k -> Cqk (coalesced), v -> VtG (packed 8B transposed stores)
  gemm_kernel<3, 128><<<dim3(48, 32), 256, 0, stream>>>(h, W, Cqk, nullptr, nullptr, nullptr, VtG, 4096, 6144, 2048, 4096);
  // 4. attention (LDS-staged, swizzled, conflict-free)
  attn_kernel<<<dim3(16, 16, 2), 256, 0, stream>>>(Cqk, VtG, obuf);
  // 5-6. x1 = x + o @ W_o^T
  dequant_kernel<<<2048, 256, 0, stream>>>(o_qw, o_sc, o_zp, o_A, o_B, W, 2048, 2048);
  gemm_kernel<1, 64><<<dim3(32, 32), 256, 0, stream>>>(obuf, W, nullptr, x1, x, nullptr, nullptr, 4096, 2048, 2048, 2048);
  // 7. h2 = LN2(x1)
  ln_kernel<<<4096, 256, 0, stream>>>(x1, ln2w, ln2b, h);
  // 8-9. g = h2 @ W_g^T  (C reused as 4096x8192)
  dequant_kernel<<<8192, 256, 0, stream>>>(g_qw, g_sc, g_zp, g_A, g_B, W, 8192, 2048);
  gemm_kernel<0, 128><<<dim3(64, 32), 256, 0, stream>>>(h, W, C, nullptr, nullptr, nullptr, nullptr, 4096, 8192, 2048, 8192);
  // 10-11. ff = silu(g) * (h2 @ W_u^T), fused epilogue, in-place over C
  dequant_kernel<<<8192, 256, 0, stream>>>(u_qw, u_sc, u_zp, u_A, u_B, W, 8192, 2048);
  gemm_kernel<2, 128><<<dim3(64, 32), 256, 0, stream>>>(h, W, C, nullptr, nullptr, C, nullptr, 4096, 8192, 2048, 8192);
  // 12-13. out = x1 + ff @ W_d^T  (plain MODE 1, no atomics)
  dequant_kernel<<<8192, 256, 0, stream>>>(d_qw, d_sc, d_zp, d_A, d_B, W, 2048, 8192);
  gemm_kernel<1, 64><<<dim3(32, 32), 256, 0, stream>>>(C, W, nullptr, out, x1, nullptr, nullptr, 4096, 2048, 8192, 2048);
}

// Round 5
// 1291.391 us; speedup vs baseline: 1.4923x; 1.1989x over previous
//
#include <hip/hip_runtime.h>
#include <cstdint>
#include <cstddef>

#define GLOBAL_AS __attribute__((address_space(1)))
#define LDS_AS    __attribute__((address_space(3)))

typedef __bf16 bf16;
typedef __bf16 bf16x4 __attribute__((ext_vector_type(4)));
typedef __bf16 bf16x8 __attribute__((ext_vector_type(8)));
typedef float  f32x4  __attribute__((ext_vector_type(4)));

__device__ __forceinline__ void gl_lds16(const void* g, void* l) {
  // 16B-per-lane async global->LDS; LDS dest = wave-uniform base + lane*16
  __builtin_amdgcn_global_load_lds((GLOBAL_AS void*)g, (LDS_AS void*)l, 16, 0, 0);
}

// ---------------- LayerNorm: fp32 (rows of 2048) -> bf16 ----------------
__global__ __launch_bounds__(256) void ln_kernel(const float* __restrict__ x,
                                                 const float* __restrict__ w,
                                                 const float* __restrict__ bias,
                                                 bf16* __restrict__ out) {
  const int row = blockIdx.x;
  const int tid = threadIdx.x;
  const float* xr = x + (size_t)row * 2048;
  f32x4 v0 = ((const f32x4*)xr)[tid * 2];
  f32x4 v1 = ((const f32x4*)xr)[tid * 2 + 1];
  float s = 0.f, ss = 0.f;
#pragma unroll
  for (int j = 0; j < 4; ++j) { s += v0[j]; ss += v0[j] * v0[j]; }
#pragma unroll
  for (int j = 0; j < 4; ++j) { s += v1[j]; ss += v1[j] * v1[j]; }
#pragma unroll
  for (int d = 1; d < 64; d <<= 1) { s += __shfl_xor(s, d); ss += __shfl_xor(ss, d); }
  __shared__ float red[8];
  const int wave = tid >> 6, lane = tid & 63;
  if (lane == 0) { red[wave * 2] = s; red[wave * 2 + 1] = ss; }
  __syncthreads();
  s  = red[0] + red[2] + red[4] + red[6];
  ss = red[1] + red[3] + red[5] + red[7];
  const float mean = s * (1.f / 2048.f);
  const float var  = ss * (1.f / 2048.f) - mean * mean;  // biased, matches jnp var
  const float rstd = rsqrtf(var + 1e-5f);
  const int col = tid * 8;
  bf16x8 o;
#pragma unroll
  for (int j = 0; j < 4; ++j) o[j]     = (bf16)((v0[j] - mean) * rstd * w[col + j]     + bias[col + j]);
#pragma unroll
  for (int j = 0; j < 4; ++j) o[4 + j] = (bf16)((v1[j] - mean) * rstd * w[col + 4 + j] + bias[col + 4 + j]);
  *(bf16x8*)(out + (size_t)row * 2048 + col) = o;
}

// -------- Dequant + LoRA fold: W[o,i] = qw*sc[o]+zp[o]+2*(B@A)[o,i] --------
__global__ __launch_bounds__(256) void dequant_kernel(const int* __restrict__ qw,
    const float* __restrict__ sc, const float* __restrict__ zp,
    const float* __restrict__ A, const float* __restrict__ Bm,
    bf16* __restrict__ W, int out_f, int in_f) {
  const int per_row = in_f >> 3;
  const int idx = blockIdx.x * 256 + threadIdx.x;   // grid sized exactly out_f*in_f/8/256
  const int o  = idx / per_row;
  const int i0 = (idx - o * per_row) << 3;
  const float s = sc[o], z = zp[o];
  float bl[16];
#pragma unroll
  for (int r = 0; r < 16; ++r) bl[r] = Bm[o * 16 + r];
  float acc[8] = {0.f, 0.f, 0.f, 0.f, 0.f, 0.f, 0.f, 0.f};
#pragma unroll
  for (int r = 0; r < 16; ++r) {
    const f32x4* ap = (const f32x4*)(A + (size_t)r * in_f + i0);
    f32x4 a0 = ap[0], a1 = ap[1];
#pragma unroll
    for (int j = 0; j < 4; ++j) { acc[j] += bl[r] * a0[j]; acc[4 + j] += bl[r] * a1[j]; }
  }
  const int* qp = qw + (size_t)o * in_f + i0;
  bf16x8 w8;
#pragma unroll
  for (int j = 0; j < 8; ++j) w8[j] = (bf16)((float)qp[j] * s + z + 2.f * acc[j]);
  *(bf16x8*)(W + (size_t)o * in_f + i0) = w8;
}

// -------- bf16 GEMM: C[M,N] = A[M,K] @ B[N,K]^T, 128x128 tile, BK=64 --------
// LDS tiles XOR-swizzled: 16B chunk c of row s lives at slot c ^ (s&7), so
// fragment ds_read_b128 (16 lcol lanes, 128B row stride) spread over all banks.
// MODE 0: Cb = bf16(acc)                       (ldc = N)
// MODE 1: Cf = res + acc (fp32 residual add; res may alias Cf)
// MODE 2: Cb = silu(gate)*acc (gate may alias Cb)
// MODE 3: qkv epilogue: cols<4096 -> Cb=Cqk (ldc=4096); cols>=4096 -> V^T packed 8B store to vt
template <int MODE>
__global__ __launch_bounds__(256) void gemm_kernel(const bf16* __restrict__ A,
    const bf16* __restrict__ B, bf16* __restrict__ Cb, float* __restrict__ Cf,
    const float* __restrict__ res, const bf16* __restrict__ gate, bf16* __restrict__ vt,
    int M, int N, int K, int ldc) {
  const int n0 = blockIdx.x * 128;
  const int m0 = blockIdx.y * 128;
  const int tid = threadIdx.x;
  const int wave = tid >> 6, lane = tid & 63;
  const int lcol = lane & 15, lrow = lane >> 4;
  const int wm = (wave >> 1) * 64, wn = (wave & 1) * 64;
  __shared__ bf16 As[128 * 64];
  __shared__ bf16 Bs[128 * 64];
  f32x4 acc[4][4] = {};
  // staging source chunk permutation: lane l covers row (l>>3), chunk (l&7);
  // LDS slot (row, c) must hold source chunk c ^ (row&7)
  const int sw = (((lane & 7) ^ ((lane >> 3) & 7))) * 8;
  const bf16* Ag = A + (size_t)(m0 + wave * 32 + (lane >> 3)) * K + sw;
  const bf16* Bg = B + (size_t)(n0 + wave * 32 + (lane >> 3)) * K + sw;
  for (int kt = 0; kt < K; kt += 64) {
#pragma unroll
    for (int r8 = 0; r8 < 4; ++r8) {
      gl_lds16(Ag + (size_t)r8 * 8 * K + kt, As + (wave * 32 + r8 * 8) * 64);
      gl_lds16(Bg + (size_t)r8 * 8 * K + kt, Bs + (wave * 32 + r8 * 8) * 64);
    }
    __syncthreads();
#pragma unroll
    for (int ks = 0; ks < 2; ++ks) {
      bf16x8 af[4], bfr[4];
#pragma unroll
      for (int i = 0; i < 4; ++i)
        af[i]  = *(const bf16x8*)(As + (wm + i * 16 + lcol) * 64 + ((ks * 4 + lrow) ^ (lcol & 7)) * 8);
#pragma unroll
      for (int j = 0; j < 4; ++j)
        bfr[j] = *(const bf16x8*)(Bs + (wn + j * 16 + lcol) * 64 + ((ks * 4 + lrow) ^ (lcol & 7)) * 8);
#pragma unroll
      for (int i = 0; i < 4; ++i)
#pragma unroll
        for (int j = 0; j < 4; ++j)
          acc[i][j] = __builtin_amdgcn_mfma_f32_16x16x32_bf16(af[i], bfr[j], acc[i][j], 0, 0, 0);
    }
    __syncthreads();
  }
#pragma unroll
  for (int i = 0; i < 4; ++i)
#pragma unroll
    for (int j = 0; j < 4; ++j) {
      const int row0 = m0 + wm + i * 16 + lrow * 4;      // C/D: row = quad*4+reg
      const int col  = n0 + wn + j * 16 + lcol;          //      col = lane&15
      if (MODE == 3 && col >= 4096) {
        // v -> V^T[(b*16+h)*128+d][s]; 4 consecutive s per lane -> packed 8B store
        const int c2 = col - 4096;
        bf16x4 v4;
#pragma unroll
        for (int r = 0; r < 4; ++r) v4[r] = (bf16)acc[i][j][r];
        *(bf16x4*)(vt + (size_t)(((row0 >> 11) * 16 + (c2 >> 7)) * 128 + (c2 & 127)) * 2048
                      + (row0 & 2047)) = v4;
      } else {
#pragma unroll
        for (int r = 0; r < 4; ++r) {
          const int row = row0 + r;
          const float v = acc[i][j][r];
          const size_t idx = (size_t)row * ldc + col;
          if (MODE == 0)      Cb[idx] = (bf16)v;
          else if (MODE == 1) Cf[idx] = res[idx] + v;
          else if (MODE == 2) {
            const float g = (float)gate[idx];
            Cb[idx] = (bf16)((g / (1.f + __expf(-g))) * v);
          } else Cb[idx] = (bf16)v;  // MODE 3 q|k part (ldc=4096)
        }
      }
    }
}

// -------- Flash attention: Cqk [4096][4096] (q|k), VtG [(b*16+h)*128+d][2048] --------
// 128 q-rows/block (32/wave). K & V^T staged via async global->LDS with XOR-swizzled
// 16B chunks (slot = c ^ (row & mask)) so fragment ds_read_b128 spread over all banks.
__global__ __launch_bounds__(256) void attn_kernel(const bf16* __restrict__ Cqk,
                                                   const bf16* __restrict__ VtG,
                                                   bf16* __restrict__ obuf) {
  const int qt = blockIdx.x, h = blockIdx.y, b = blockIdx.z;
  const int tid = threadIdx.x, wave = tid >> 6, lane = tid & 63;
  const int lcol = lane & 15, lrow = lane >> 4;
  const int base_m = b * 2048 + qt * 128;
  __shared__ bf16 Ks[64 * 128];     // [s][d], swizzled 16B chunks (mask 15)
  __shared__ bf16 Vt[128 * 64];     // [d][s], swizzled 16B chunks (mask 7)
  __shared__ bf16 Ps[4][32 * 72];   // per-wave P, stride 72
  bf16* ps = Ps[wave];
  // Q fragments (A-layout) once, from global
  bf16x8 qf[2][4];
#pragma unroll
  for (int i = 0; i < 2; ++i)
#pragma unroll
    for (int dk = 0; dk < 4; ++dk)
      qf[i][dk] = *(const bf16x8*)(Cqk + (size_t)(base_m + wave * 32 + i * 16 + lcol) * 4096
                                   + h * 128 + dk * 32 + lrow * 8);
  f32x4 of[2][8] = {};
  float m_run[2][4], l_run[2][4];
#pragma unroll
  for (int i = 0; i < 2; ++i)
#pragma unroll
    for (int r = 0; r < 4; ++r) { m_run[i][r] = -1e30f; l_run[i][r] = 0.f; }
  const float SCL2 = 0.12751874972f;  // (1/sqrt(128)) * log2(e); exp2-domain softmax
  const int vswz = (lane & 7) ^ (lane >> 3);   // V staging chunk permutation (constant)

  for (int kt = 0; kt < 2048; kt += 64) {
    // stage K tile: wave covers s in [wave*16, wave*16+16), 4 rows (256B) per instr
#pragma unroll
    for (int r4 = 0; r4 < 4; ++r4) {
      const int s_low = r4 * 4 + lrow;                   // s & 15
      gl_lds16(Cqk + (size_t)(b * 2048 + kt + wave * 16 + s_low) * 4096 + 2048 + h * 128
                   + (lcol ^ s_low) * 8,
               Ks + (wave * 16 + r4 * 4) * 128);
    }
    // stage V^T tile: wave covers d in [wave*32, wave*32+32), 8 rows (128B) per instr
#pragma unroll
    for (int r8 = 0; r8 < 4; ++r8)
      gl_lds16(VtG + (size_t)((b * 16 + h) * 128 + wave * 32 + r8 * 8 + (lane >> 3)) * 2048
                   + kt + vswz * 8,
               Vt + (wave * 32 + r8 * 8) * 64);
    __syncthreads();

    // S = Q @ K^T  (kf slot = (4dk+lrow) ^ lcol)
    f32x4 sacc[2][4] = {};
#pragma unroll
    for (int jb = 0; jb < 4; ++jb) {
      bf16x8 kf[4];
#pragma unroll
      for (int dk = 0; dk < 4; ++dk)
        kf[dk] = *(const bf16x8*)(Ks + (jb * 16 + lcol) * 128 + ((dk * 4 + lrow) ^ lcol) * 8);
#pragma unroll
      for (int i = 0; i < 2; ++i)
#pragma unroll
        for (int dk = 0; dk < 4; ++dk)
          sacc[i][jb] = __builtin_amdgcn_mfma_f32_16x16x32_bf16(qf[i][dk], kf[dk], sacc[i][jb], 0, 0, 0);
    }

    // online softmax; row = lrow*4+r, cols over (jb, lcol); reduce over 16 lcol lanes
#pragma unroll
    for (int i = 0; i < 2; ++i) {
      float z[4][4], mx[4];
#pragma unroll
      for (int jb = 0; jb < 4; ++jb)
#pragma unroll
        for (int r = 0; r < 4; ++r) z[jb][r] = sacc[i][jb][r] * SCL2;
#pragma unroll
      for (int r = 0; r < 4; ++r)
        mx[r] = fmaxf(fmaxf(z[0][r], z[1][r]), fmaxf(z[2][r], z[3][r]));
#pragma unroll
      for (int d = 1; d < 16; d <<= 1)
#pragma unroll
        for (int r = 0; r < 4; ++r) mx[r] = fmaxf(mx[r], __shfl_xor(mx[r], d));
#pragma unroll
      for (int r = 0; r < 4; ++r) {
        const float mn = fmaxf(m_run[i][r], mx[r]);
        const float alpha = __builtin_amdgcn_exp2f(m_run[i][r] - mn);
        m_run[i][r] = mn;
        float srow = 0.f;
#pragma unroll
        for (int jb = 0; jb < 4; ++jb) {
          const float p = __builtin_amdgcn_exp2f(z[jb][r] - mn);
          z[jb][r] = p; srow += p;
        }
        l_run[i][r] = l_run[i][r] * alpha + srow;   // per-lane partial; reduce at end
#pragma unroll
        for (int db = 0; db < 8; ++db) of[i][db][r] *= alpha;
      }
      // P: C-layout regs -> per-wave LDS (no barrier; same-wave lgkmcnt ordering)
#pragma unroll
      for (int jb = 0; jb < 4; ++jb)
#pragma unroll
        for (int r = 0; r < 4; ++r)
          ps[(i * 16 + lrow * 4 + r) * 72 + jb * 16 + lcol] = (bf16)z[jb][r];
    }

    // O += P @ V  (vf slot = (4ss+lrow) ^ (lcol&7))
#pragma unroll
    for (int ss = 0; ss < 2; ++ss) {
      bf16x8 a0 = *(const bf16x8*)(ps + (0 * 16 + lcol) * 72 + ss * 32 + lrow * 8);
      bf16x8 a1 = *(const bf16x8*)(ps + (1 * 16 + lcol) * 72 + ss * 32 + lrow * 8);
#pragma unroll
      for (int db = 0; db < 8; ++db) {
        bf16x8 vf = *(const bf16x8*)(Vt + (db * 16 + lcol) * 64 + ((ss * 4 + lrow) ^ (lcol & 7)) * 8);
        of[0][db] = __builtin_amdgcn_mfma_f32_16x16x32_bf16(a0, vf, of[0][db], 0, 0, 0);
        of[1][db] = __builtin_amdgcn_mfma_f32_16x16x32_bf16(a1, vf, of[1][db], 0, 0, 0);
      }
    }
    __syncthreads();
  }
  // final: reduce per-lane l partials over the 16 lcol lanes, normalize, store
#pragma unroll
  for (int i = 0; i < 2; ++i)
#pragma unroll
    for (int r = 0; r < 4; ++r) {
      float l = l_run[i][r];
#pragma unroll
      for (int d = 1; d < 16; d <<= 1) l += __shfl_xor(l, d);
      const float inv = 1.f / l;
      const size_t rb = (size_t)(base_m + wave * 32 + i * 16 + lrow * 4 + r) * 2048 + h * 128;
#pragma unroll
      for (int db = 0; db < 8; ++db)
        obuf[rb + db * 16 + lcol] = (bf16)(of[i][db][r] * inv);
    }
}

extern "C" void kernel_launch(void* const* d_in, const int* in_sizes, int n_in,
                              void* d_out, int out_size, void* d_ws, size_t ws_size,
                              hipStream_t stream) {
  (void)in_sizes; (void)n_in; (void)out_size; (void)ws_size;
  const int*   q_qw = (const int*)d_in[0];   const float* q_sc = (const float*)d_in[1];
  const float* q_zp = (const float*)d_in[2]; const float* q_A  = (const float*)d_in[3];
  const float* q_B  = (const float*)d_in[4];
  const int*   k_qw = (const int*)d_in[5];   const float* k_sc = (const float*)d_in[6];
  const float* k_zp = (const float*)d_in[7]; const float* k_A  = (const float*)d_in[8];
  const float* k_B  = (const float*)d_in[9];
  const int*   v_qw = (const int*)d_in[10];  const float* v_sc = (const float*)d_in[11];
  const float* v_zp = (const float*)d_in[12];const float* v_A  = (const float*)d_in[13];
  const float* v_B  = (const float*)d_in[14];
  const int*   o_qw = (const int*)d_in[15];  const float* o_sc = (const float*)d_in[16];
  const float* o_zp = (const float*)d_in[17];const float* o_A  = (const float*)d_in[18];
  const float* o_B  = (const float*)d_in[19];
  const int*   g_qw = (const int*)d_in[20];  const float* g_sc = (const float*)d_in[21];
  const float* g_zp = (const float*)d_in[22];const float* g_A  = (const float*)d_in[23];
  const float* g_B  = (const float*)d_in[24];
  const int*   u_qw = (const int*)d_in[25];  const float* u_sc = (const float*)d_in[26];
  const float* u_zp = (const float*)d_in[27];const float* u_A  = (const float*)d_in[28];
  const float* u_B  = (const float*)d_in[29];
  const int*   d_qw = (const int*)d_in[30];  const float* d_sc = (const float*)d_in[31];
  const float* d_zp = (const float*)d_in[32];const float* d_A  = (const float*)d_in[33];
  const float* d_B  = (const float*)d_in[34];
  const float* x    = (const float*)d_in[35];
  const float* ln1w = (const float*)d_in[36];const float* ln1b = (const float*)d_in[37];
  const float* ln2w = (const float*)d_in[38];const float* ln2b = (const float*)d_in[39];

  // workspace arena — peak 112 MiB (W 32 + h 16 + C 64); x1 lives in d_out (fp32)
  char* ws = (char*)d_ws;
  bf16* W = (bf16*)ws;                                    // 32 MiB dequant scratch
  bf16* h = (bf16*)(ws + (size_t)32 * 1024 * 1024);       // 16 MiB LN out
  bf16* C = (bf16*)(ws + (size_t)48 * 1024 * 1024);       // 64 MiB
  bf16* Cqk = C;                                          // [4096][4096] q|k (32 MiB)
  bf16* VtG = C + (size_t)4096 * 4096;                    // [2*16*128][2048] (16 MiB)
  bf16* obuf = VtG + (size_t)2 * 16 * 128 * 2048;         // [4096][2048] (16 MiB)
  float* x1  = (float*)d_out;
  float* out = (float*)d_out;

  // 1. h = LN1(x)
  ln_kernel<<<4096, 256, 0, stream>>>(x, ln1w, ln1b, h);
  // 2. dequant W_q|W_k|W_v (6144x2048)
  dequant_kernel<<<2048, 256, 0, stream>>>(q_qw, q_sc, q_zp, q_A, q_B, W, 2048, 2048);
  dequant_kernel<<<2048, 256, 0, stream>>>(k_qw, k_sc, k_zp, k_A, k_B, W + (size_t)2048 * 2048, 2048, 2048);
  dequant_kernel<<<2048, 256, 0, stream>>>(v_qw, v_sc, v_zp, v_A, v_B, W + (size_t)4096 * 2048, 2048, 2048);
  // 3. qkv GEMM: q|k -> Cqk (coalesced), v -> VtG (packed 8B transposed stores)
  gemm_kernel<3><<<dim3(48, 32), 256, 0, stream>>>(h, W, Cqk, nullptr, nullptr, nullptr, VtG, 4096, 6144, 2048, 4096);
  // 4. attention (LDS-staged, swizzled, conflict-free)
  attn_kernel<<<dim3(16, 16, 2), 256, 0, stream>>>(Cqk, VtG, obuf);
  // 5-6. x1 = x + o @ W_o^T
  dequant_kernel<<<2048, 256, 0, stream>>>(o_qw, o_sc, o_zp, o_A, o_B, W, 2048, 2048);
  gemm_kernel<1><<<dim3(16, 32), 256, 0, stream>>>(obuf, W, nullptr, x1, x, nullptr, nullptr, 4096, 2048, 2048, 2048);
  // 7. h2 = LN2(x1)
  ln_kernel<<<4096, 256, 0, stream>>>(x1, ln2w, ln2b, h);
  // 8-9. g = h2 @ W_g^T  (C reused as 4096x8192)
  dequant_kernel<<<8192, 256, 0, stream>>>(g_qw, g_sc, g_zp, g_A, g_B, W, 8192, 2048);
  gemm_kernel<0><<<dim3(64, 32), 256, 0, stream>>>(h, W, C, nullptr, nullptr, nullptr, nullptr, 4096, 8192, 2048, 8192);
  // 10-11. ff = silu(g) * (h2 @ W_u^T), fused epilogue, in-place over C
  dequant_kernel<<<8192, 256, 0, stream>>>(u_qw, u_sc, u_zp, u_A, u_B, W, 8192, 2048);
  gemm_kernel<2><<<dim3(64, 32), 256, 0, stream>>>(h, W, C, nullptr, nullptr, C, nullptr, 4096, 8192, 2048, 8192);
  // 12-13. out = x1 + ff @ W_d^T
  dequant_kernel<<<8192, 256, 0, stream>>>(d_qw, d_sc, d_zp, d_A, d_B, W, 2048, 8192);
  gemm_kernel<1><<<dim3(16, 32), 256, 0, stream>>>(C, W, nullptr, out, x1, nullptr, nullptr, 4096, 2048, 8192, 2048);
}

// Round 7
// 1183.177 us; speedup vs baseline: 1.6288x; 1.0915x over previous
//
#include <hip/hip_runtime.h>
#include <cstdint>
#include <cstddef>

#define GLOBAL_AS __attribute__((address_space(1)))
#define LDS_AS    __attribute__((address_space(3)))

typedef __bf16 bf16;
typedef __bf16 bf16x4 __attribute__((ext_vector_type(4)));
typedef __bf16 bf16x8 __attribute__((ext_vector_type(8)));
typedef float  f32x4  __attribute__((ext_vector_type(4)));
typedef int    i32x4  __attribute__((ext_vector_type(4)));
typedef unsigned int u32x2 __attribute__((ext_vector_type(2)));

__device__ __forceinline__ void gl_lds16(const void* g, void* l) {
  // 16B-per-lane async global->LDS; LDS dest = wave-uniform base + lane*16
  __builtin_amdgcn_global_load_lds((GLOBAL_AS void*)g, (LDS_AS void*)l, 16, 0, 0);
}

// ---------------- LayerNorm: fp32 (rows of 2048) -> bf16 ----------------
__global__ __launch_bounds__(256) void ln_kernel(const float* __restrict__ x,
                                                 const float* __restrict__ w,
                                                 const float* __restrict__ bias,
                                                 bf16* __restrict__ out) {
  const int row = blockIdx.x;
  const int tid = threadIdx.x;
  const float* xr = x + (size_t)row * 2048;
  f32x4 v0 = ((const f32x4*)xr)[tid * 2];
  f32x4 v1 = ((const f32x4*)xr)[tid * 2 + 1];
  float s = 0.f, ss = 0.f;
#pragma unroll
  for (int j = 0; j < 4; ++j) { s += v0[j]; ss += v0[j] * v0[j]; }
#pragma unroll
  for (int j = 0; j < 4; ++j) { s += v1[j]; ss += v1[j] * v1[j]; }
#pragma unroll
  for (int d = 1; d < 64; d <<= 1) { s += __shfl_xor(s, d); ss += __shfl_xor(ss, d); }
  __shared__ float red[8];
  const int wave = tid >> 6, lane = tid & 63;
  if (lane == 0) { red[wave * 2] = s; red[wave * 2 + 1] = ss; }
  __syncthreads();
  s  = red[0] + red[2] + red[4] + red[6];
  ss = red[1] + red[3] + red[5] + red[7];
  const float mean = s * (1.f / 2048.f);
  const float var  = ss * (1.f / 2048.f) - mean * mean;  // biased, matches jnp var
  const float rstd = rsqrtf(var + 1e-5f);
  const int col = tid * 8;
  bf16x8 o;
#pragma unroll
  for (int j = 0; j < 4; ++j) o[j]     = (bf16)((v0[j] - mean) * rstd * w[col + j]     + bias[col + j]);
#pragma unroll
  for (int j = 0; j < 4; ++j) o[4 + j] = (bf16)((v1[j] - mean) * rstd * w[col + 4 + j] + bias[col + 4 + j]);
  *(bf16x8*)(out + (size_t)row * 2048 + col) = o;
}

// ---------------- LayerNorm + int8 row-quantize (for i8 GEMM path) ----------------
// qh = rint(y*127/absmax), s_m = absmax/127, rs = sum(y), de = rs - s_m*sum(qh)
__global__ __launch_bounds__(256) void ln_q_kernel(const float* __restrict__ x,
    const float* __restrict__ w, const float* __restrict__ bias,
    char* __restrict__ qh, float* __restrict__ s_m, float* __restrict__ rs,
    float* __restrict__ de) {
  const int row = blockIdx.x;
  const int tid = threadIdx.x;
  const float* xr = x + (size_t)row * 2048;
  f32x4 v0 = ((const f32x4*)xr)[tid * 2];
  f32x4 v1 = ((const f32x4*)xr)[tid * 2 + 1];
  float s = 0.f, ss = 0.f;
#pragma unroll
  for (int j = 0; j < 4; ++j) { s += v0[j]; ss += v0[j] * v0[j]; }
#pragma unroll
  for (int j = 0; j < 4; ++j) { s += v1[j]; ss += v1[j] * v1[j]; }
#pragma unroll
  for (int d = 1; d < 64; d <<= 1) { s += __shfl_xor(s, d); ss += __shfl_xor(ss, d); }
  __shared__ float red[12];
  const int wave = tid >> 6, lane = tid & 63;
  if (lane == 0) { red[wave * 2] = s; red[wave * 2 + 1] = ss; }
  __syncthreads();
  s  = red[0] + red[2] + red[4] + red[6];
  ss = red[1] + red[3] + red[5] + red[7];
  const float mean = s * (1.f / 2048.f);
  const float var  = ss * (1.f / 2048.f) - mean * mean;
  const float rstd = rsqrtf(var + 1e-5f);
  const int col = tid * 8;
  float y[8];
#pragma unroll
  for (int j = 0; j < 4; ++j) y[j]     = (v0[j] - mean) * rstd * w[col + j]     + bias[col + j];
#pragma unroll
  for (int j = 0; j < 4; ++j) y[4 + j] = (v1[j] - mean) * rstd * w[col + 4 + j] + bias[col + 4 + j];
  float sy = 0.f, mx = 0.f;
#pragma unroll
  for (int j = 0; j < 8; ++j) { sy += y[j]; mx = fmaxf(mx, fabsf(y[j])); }
#pragma unroll
  for (int d = 1; d < 64; d <<= 1) { sy += __shfl_xor(sy, d); mx = fmaxf(mx, __shfl_xor(mx, d)); }
  __syncthreads();  // red reuse
  if (lane == 0) { red[wave * 2] = sy; red[wave * 2 + 1] = mx; }
  __syncthreads();
  const float sya = red[0] + red[2] + red[4] + red[6];
  const float mxa = fmaxf(fmaxf(red[1], red[3]), fmaxf(red[5], red[7]));
  const float inv = 127.f / fmaxf(mxa, 1e-8f);
  unsigned int lo = 0, hi = 0;
  int qs = 0;
#pragma unroll
  for (int j = 0; j < 4; ++j) { int qi = (int)rintf(y[j] * inv);     qs += qi; lo |= ((unsigned int)qi & 0xffu) << (8 * j); }
#pragma unroll
  for (int j = 0; j < 4; ++j) { int qi = (int)rintf(y[4 + j] * inv); qs += qi; hi |= ((unsigned int)qi & 0xffu) << (8 * j); }
  u32x2 st; st[0] = lo; st[1] = hi;
  *(u32x2*)(qh + (size_t)row * 2048 + col) = st;
  float fqs = (float)qs;
#pragma unroll
  for (int d = 1; d < 64; d <<= 1) fqs += __shfl_xor(fqs, d);
  __syncthreads();
  if (lane == 0) red[8 + wave] = fqs;
  __syncthreads();
  if (tid == 0) {
    const float qsa = red[8] + red[9] + red[10] + red[11];
    const float smv = fmaxf(mxa, 1e-8f) / 127.f;
    s_m[row] = smv; rs[row] = sya; de[row] = sya - smv * qsa;
  }
}

// -------- Dequant + LoRA fold: W[o,i] = qw*sc[o]+zp[o]+2*(B@A)[o,i] --------
__global__ __launch_bounds__(256) void dequant_kernel(const int* __restrict__ qw,
    const float* __restrict__ sc, const float* __restrict__ zp,
    const float* __restrict__ A, const float* __restrict__ Bm,
    bf16* __restrict__ W, int out_f, int in_f) {
  const int per_row = in_f >> 3;
  const int idx = blockIdx.x * 256 + threadIdx.x;
  const int o  = idx / per_row;
  const int i0 = (idx - o * per_row) << 3;
  const float s = sc[o], z = zp[o];
  float bl[16];
#pragma unroll
  for (int r = 0; r < 16; ++r) bl[r] = Bm[o * 16 + r];
  float acc[8] = {0.f, 0.f, 0.f, 0.f, 0.f, 0.f, 0.f, 0.f};
#pragma unroll
  for (int r = 0; r < 16; ++r) {
    const f32x4* ap = (const f32x4*)(A + (size_t)r * in_f + i0);
    f32x4 a0 = ap[0], a1 = ap[1];
#pragma unroll
    for (int j = 0; j < 4; ++j) { acc[j] += bl[r] * a0[j]; acc[4 + j] += bl[r] * a1[j]; }
  }
  const int* qp = qw + (size_t)o * in_f + i0;
  bf16x8 w8;
#pragma unroll
  for (int j = 0; j < 8; ++j) w8[j] = (bf16)((float)qp[j] * s + z + 2.f * acc[j]);
  *(bf16x8*)(W + (size_t)o * in_f + i0) = w8;
}

// -------- int32 -> int8 weight pack + per-row mean weight (one 2048-row per block) --------
// wsum[o] = sc[o] * (sum_i qw[o,i]) / 2048
__global__ __launch_bounds__(256) void pack_w_kernel(const int* __restrict__ qw,
    const float* __restrict__ sc, char* __restrict__ out, float* __restrict__ wsum) {
  const int row = blockIdx.x;
  const int tid = threadIdx.x;
  const size_t idx = (size_t)row * 2048 + tid * 8;
  i32x4 a = *(const i32x4*)(qw + idx);
  i32x4 b = *(const i32x4*)(qw + idx + 4);
  unsigned int lo = ((unsigned)a[0] & 0xffu) | (((unsigned)a[1] & 0xffu) << 8) |
                    (((unsigned)a[2] & 0xffu) << 16) | (((unsigned)a[3] & 0xffu) << 24);
  unsigned int hi = ((unsigned)b[0] & 0xffu) | (((unsigned)b[1] & 0xffu) << 8) |
                    (((unsigned)b[2] & 0xffu) << 16) | (((unsigned)b[3] & 0xffu) << 24);
  u32x2 st; st[0] = lo; st[1] = hi;
  *(u32x2*)(out + idx) = st;
  float fs = (float)(a[0] + a[1] + a[2] + a[3] + b[0] + b[1] + b[2] + b[3]);
#pragma unroll
  for (int d = 1; d < 64; d <<= 1) fs += __shfl_xor(fs, d);
  __shared__ float red[4];
  const int wave = tid >> 6, lane = tid & 63;
  if (lane == 0) red[wave] = fs;
  __syncthreads();
  if (tid == 0) wsum[row] = sc[row] * (red[0] + red[1] + red[2] + red[3]) * (1.f / 2048.f);
}

// -------- LoRA B matrices -> bf16 [N][32], x2 scale, zero-padded per matrix --------
__global__ __launch_bounds__(256) void pack_b2_kernel(const float* __restrict__ gB,
    const float* __restrict__ uB, bf16* __restrict__ B2g, bf16* __restrict__ B2u) {
  const int idx = blockIdx.x * 256 + threadIdx.x;   // 8192*32
  const int nn = idx >> 5, r = idx & 31;
  B2g[idx] = (r < 16)  ? (bf16)(2.f * gB[nn * 16 + r])        : (bf16)0.f;
  B2u[idx] = (r >= 16) ? (bf16)(2.f * uB[nn * 16 + (r - 16)]) : (bf16)0.f;
}

// -------- hA[m][0..32) = s_m * (qh @ [Ag|Au].T), bf16 --------
__global__ __launch_bounds__(256) void hA_kernel(const char* __restrict__ qh,
    const float* __restrict__ s_m, const float* __restrict__ Ag,
    const float* __restrict__ Au, bf16* __restrict__ hA) {
  __shared__ bf16 Asm[32 * 512];
  const int tid = threadIdx.x, wave = tid >> 6, lane = tid & 63;
  const int row = blockIdx.x * 4 + wave;
  float acc[32];
#pragma unroll
  for (int r = 0; r < 32; ++r) acc[r] = 0.f;
  for (int kb = 0; kb < 2048; kb += 512) {
    const int r2 = tid >> 3, c0 = (tid & 7) * 64;
    const float* src = (r2 < 16 ? Ag + (size_t)r2 * 2048 : Au + (size_t)(r2 - 16) * 2048) + kb + c0;
#pragma unroll
    for (int j = 0; j < 64; j += 8) {
      f32x4 va = *(const f32x4*)(src + j);
      f32x4 vb = *(const f32x4*)(src + j + 4);
      bf16x8 bv;
#pragma unroll
      for (int jj = 0; jj < 4; ++jj) { bv[jj] = (bf16)va[jj]; bv[4 + jj] = (bf16)vb[jj]; }
      *(bf16x8*)(Asm + r2 * 512 + c0 + j) = bv;
    }
    __syncthreads();
    float q[8];
    const char* qp = qh + (size_t)row * 2048 + kb + lane * 8;
#pragma unroll
    for (int j = 0; j < 8; ++j) q[j] = (float)qp[j];
#pragma unroll
    for (int r = 0; r < 32; ++r) {
      bf16x8 a8 = *(const bf16x8*)(Asm + r * 512 + lane * 8);
      float d = 0.f;
#pragma unroll
      for (int j = 0; j < 8; ++j) d += q[j] * (float)a8[j];
      acc[r] += d;
    }
    __syncthreads();
  }
  const float s = s_m[row];
#pragma unroll
  for (int r = 0; r < 32; ++r) {
    float v = acc[r];
#pragma unroll
    for (int d = 1; d < 64; d <<= 1) v += __shfl_xor(v, d);
    if (lane == 0) hA[(size_t)row * 32 + r] = (bf16)(s * v);
  }
}

// -------- bf16 GEMM: C[M,N] = A[M,K] @ B[N,K]^T, 128x128 tile, BK=64, swizzled LDS --------
// MODE 0: Cb = bf16(acc); MODE 1: Cf = res + acc; MODE 2: Cb = silu(gate)*acc;
// MODE 3: qkv epilogue (q|k -> Cb ldc=4096, v -> V^T packed 8B store)
template <int MODE>
__global__ __launch_bounds__(256) void gemm_kernel(const bf16* __restrict__ A,
    const bf16* __restrict__ B, bf16* __restrict__ Cb, float* __restrict__ Cf,
    const float* __restrict__ res, const bf16* __restrict__ gate, bf16* __restrict__ vt,
    int M, int N, int K, int ldc) {
  const int n0 = blockIdx.x * 128;
  const int m0 = blockIdx.y * 128;
  const int tid = threadIdx.x;
  const int wave = tid >> 6, lane = tid & 63;
  const int lcol = lane & 15, lrow = lane >> 4;
  const int wm = (wave >> 1) * 64, wn = (wave & 1) * 64;
  __shared__ bf16 As[128 * 64];
  __shared__ bf16 Bs[128 * 64];
  f32x4 acc[4][4] = {};
  const int sw = (((lane & 7) ^ ((lane >> 3) & 7))) * 8;
  const bf16* Ag = A + (size_t)(m0 + wave * 32 + (lane >> 3)) * K + sw;
  const bf16* Bg = B + (size_t)(n0 + wave * 32 + (lane >> 3)) * K + sw;
  for (int kt = 0; kt < K; kt += 64) {
#pragma unroll
    for (int r8 = 0; r8 < 4; ++r8) {
      gl_lds16(Ag + (size_t)r8 * 8 * K + kt, As + (wave * 32 + r8 * 8) * 64);
      gl_lds16(Bg + (size_t)r8 * 8 * K + kt, Bs + (wave * 32 + r8 * 8) * 64);
    }
    __syncthreads();
#pragma unroll
    for (int ks = 0; ks < 2; ++ks) {
      bf16x8 af[4], bfr[4];
#pragma unroll
      for (int i = 0; i < 4; ++i)
        af[i]  = *(const bf16x8*)(As + (wm + i * 16 + lcol) * 64 + ((ks * 4 + lrow) ^ (lcol & 7)) * 8);
#pragma unroll
      for (int j = 0; j < 4; ++j)
        bfr[j] = *(const bf16x8*)(Bs + (wn + j * 16 + lcol) * 64 + ((ks * 4 + lrow) ^ (lcol & 7)) * 8);
#pragma unroll
      for (int i = 0; i < 4; ++i)
#pragma unroll
        for (int j = 0; j < 4; ++j)
          acc[i][j] = __builtin_amdgcn_mfma_f32_16x16x32_bf16(af[i], bfr[j], acc[i][j], 0, 0, 0);
    }
    __syncthreads();
  }
#pragma unroll
  for (int i = 0; i < 4; ++i)
#pragma unroll
    for (int j = 0; j < 4; ++j) {
      const int row0 = m0 + wm + i * 16 + lrow * 4;
      const int col  = n0 + wn + j * 16 + lcol;
      if (MODE == 3 && col >= 4096) {
        const int c2 = col - 4096;
        bf16x4 v4;
#pragma unroll
        for (int r = 0; r < 4; ++r) v4[r] = (bf16)acc[i][j][r];
        *(bf16x4*)(vt + (size_t)(((row0 >> 11) * 16 + (c2 >> 7)) * 128 + (c2 & 127)) * 2048
                      + (row0 & 2047)) = v4;
      } else {
#pragma unroll
        for (int r = 0; r < 4; ++r) {
          const int row = row0 + r;
          const float v = acc[i][j][r];
          const size_t idx = (size_t)row * ldc + col;
          if (MODE == 0)      Cb[idx] = (bf16)v;
          else if (MODE == 1) Cf[idx] = res[idx] + v;
          else if (MODE == 2) {
            const float g = (float)gate[idx];
            Cb[idx] = (bf16)((g / (1.f + __expf(-g))) * v);
          } else Cb[idx] = (bf16)v;
        }
      }
    }
}

// -------- int8 GEMM with dequant epilogue: 128x128 tile, BK=128, swizzled LDS --------
// out[m,o] = sc[o]*s_m[m]*(qh@qw^T) + zp[o]*rs[m] + wsum[o]*de[m] + (hA@B2^T)
// (wsum*de removes the correlated activation-quantization error: de = sum(h)-s_m*sum(qh))
// MODE 0: store bf16.  MODE 1: store silu(gate)*val (gate may alias Cb).
template <int MODE>
__global__ __launch_bounds__(256) void gemm_i8_kernel(const char* __restrict__ Aq,
    const char* __restrict__ Bq, const float* __restrict__ s_m, const float* __restrict__ rs,
    const float* __restrict__ de, const float* __restrict__ sc, const float* __restrict__ zp,
    const float* __restrict__ wsum, const bf16* __restrict__ hA, const bf16* __restrict__ B2,
    bf16* __restrict__ Cb, const bf16* __restrict__ gate, int M, int N, int K) {
  const int n0 = blockIdx.x * 128;
  const int m0 = blockIdx.y * 128;
  const int tid = threadIdx.x;
  const int wave = tid >> 6, lane = tid & 63;
  const int lcol = lane & 15, lrow = lane >> 4;
  const int wm = (wave >> 1) * 64, wn = (wave & 1) * 64;
  __shared__ char As[128 * 128];
  __shared__ char Bs[128 * 128];
  i32x4 acc[4][4] = {};
  const int sw = (((lane & 7) ^ ((lane >> 3) & 7))) * 16;   // byte swizzle, 16B chunks
  const char* Ag = Aq + (size_t)(m0 + wave * 32 + (lane >> 3)) * K + sw;
  const char* Bg = Bq + (size_t)(n0 + wave * 32 + (lane >> 3)) * K + sw;
  for (int kt = 0; kt < K; kt += 128) {
#pragma unroll
    for (int r8 = 0; r8 < 4; ++r8) {
      gl_lds16(Ag + (size_t)r8 * 8 * K + kt, As + (wave * 32 + r8 * 8) * 128);
      gl_lds16(Bg + (size_t)r8 * 8 * K + kt, Bs + (wave * 32 + r8 * 8) * 128);
    }
    __syncthreads();
#pragma unroll
    for (int ks = 0; ks < 2; ++ks) {
      i32x4 af[4], bfr[4];
#pragma unroll
      for (int i = 0; i < 4; ++i)
        af[i]  = *(const i32x4*)(As + (wm + i * 16 + lcol) * 128 + (((ks * 4 + lrow) ^ (lcol & 7))) * 16);
#pragma unroll
      for (int j = 0; j < 4; ++j)
        bfr[j] = *(const i32x4*)(Bs + (wn + j * 16 + lcol) * 128 + (((ks * 4 + lrow) ^ (lcol & 7))) * 16);
#pragma unroll
      for (int i = 0; i < 4; ++i)
#pragma unroll
        for (int j = 0; j < 4; ++j)
          acc[i][j] = __builtin_amdgcn_mfma_i32_16x16x64_i8(af[i], bfr[j], acc[i][j], 0, 0, 0);
    }
    __syncthreads();
  }
  // epilogue: LoRA via one bf16 MFMA per tile (K=32 over hA/B2), then affine dequant
  bf16x8 ha[4], bb[4];
#pragma unroll
  for (int i = 0; i < 4; ++i) ha[i] = *(const bf16x8*)(hA + (size_t)(m0 + wm + i * 16 + lcol) * 32 + lrow * 8);
#pragma unroll
  for (int j = 0; j < 4; ++j) bb[j] = *(const bf16x8*)(B2 + (size_t)(n0 + wn + j * 16 + lcol) * 32 + lrow * 8);
  float scv[4], zpv[4], wsv[4];
#pragma unroll
  for (int j = 0; j < 4; ++j) {
    const int col = n0 + wn + j * 16 + lcol;
    scv[j] = sc[col]; zpv[j] = zp[col]; wsv[j] = wsum[col];
  }
  float smv[4][4], rsv[4][4], dev[4][4];
#pragma unroll
  for (int i = 0; i < 4; ++i)
#pragma unroll
    for (int r = 0; r < 4; ++r) {
      const int row = m0 + wm + i * 16 + lrow * 4 + r;
      smv[i][r] = s_m[row]; rsv[i][r] = rs[row]; dev[i][r] = de[row];
    }
  const f32x4 zero = {0.f, 0.f, 0.f, 0.f};
#pragma unroll
  for (int i = 0; i < 4; ++i)
#pragma unroll
    for (int j = 0; j < 4; ++j) {
      f32x4 L = __builtin_amdgcn_mfma_f32_16x16x32_bf16(ha[i], bb[j], zero, 0, 0, 0);
#pragma unroll
      for (int r = 0; r < 4; ++r) {
        const int row = m0 + wm + i * 16 + lrow * 4 + r;
        const int col = n0 + wn + j * 16 + lcol;
        const float v = scv[j] * smv[i][r] * (float)acc[i][j][r] + zpv[j] * rsv[i][r]
                      + wsv[j] * dev[i][r] + L[r];
        const size_t idx = (size_t)row * N + col;
        if (MODE == 0) Cb[idx] = (bf16)v;
        else {
          const float g = (float)gate[idx];
          Cb[idx] = (bf16)((g / (1.f + __expf(-g))) * v);
        }
      }
    }
}

// -------- Flash attention: Cqk [4096][4096] (q|k), VtG [(b*16+h)*128+d][2048] --------
__global__ __launch_bounds__(256) void attn_kernel(const bf16* __restrict__ Cqk,
                                                   const bf16* __restrict__ VtG,
                                                   bf16* __restrict__ obuf) {
  const int qt = blockIdx.x, h = blockIdx.y, b = blockIdx.z;
  const int tid = threadIdx.x, wave = tid >> 6, lane = tid & 63;
  const int lcol = lane & 15, lrow = lane >> 4;
  const int base_m = b * 2048 + qt * 128;
  __shared__ bf16 Ks[64 * 128];
  __shared__ bf16 Vt[128 * 64];
  __shared__ bf16 Ps[4][32 * 72];
  bf16* ps = Ps[wave];
  bf16x8 qf[2][4];
#pragma unroll
  for (int i = 0; i < 2; ++i)
#pragma unroll
    for (int dk = 0; dk < 4; ++dk)
      qf[i][dk] = *(const bf16x8*)(Cqk + (size_t)(base_m + wave * 32 + i * 16 + lcol) * 4096
                                   + h * 128 + dk * 32 + lrow * 8);
  f32x4 of[2][8] = {};
  float m_run[2][4], l_run[2][4];
#pragma unroll
  for (int i = 0; i < 2; ++i)
#pragma unroll
    for (int r = 0; r < 4; ++r) { m_run[i][r] = -1e30f; l_run[i][r] = 0.f; }
  const float SCL2 = 0.12751874972f;
  const int vswz = (lane & 7) ^ (lane >> 3);

  for (int kt = 0; kt < 2048; kt += 64) {
#pragma unroll
    for (int r4 = 0; r4 < 4; ++r4) {
      const int s_low = r4 * 4 + lrow;
      gl_lds16(Cqk + (size_t)(b * 2048 + kt + wave * 16 + s_low) * 4096 + 2048 + h * 128
                   + (lcol ^ s_low) * 8,
               Ks + (wave * 16 + r4 * 4) * 128);
    }
#pragma unroll
    for (int r8 = 0; r8 < 4; ++r8)
      gl_lds16(VtG + (size_t)((b * 16 + h) * 128 + wave * 32 + r8 * 8 + (lane >> 3)) * 2048
                   + kt + vswz * 8,
               Vt + (wave * 32 + r8 * 8) * 64);
    __syncthreads();

    f32x4 sacc[2][4] = {};
#pragma unroll
    for (int jb = 0; jb < 4; ++jb) {
      bf16x8 kf[4];
#pragma unroll
      for (int dk = 0; dk < 4; ++dk)
        kf[dk] = *(const bf16x8*)(Ks + (jb * 16 + lcol) * 128 + ((dk * 4 + lrow) ^ lcol) * 8);
#pragma unroll
      for (int i = 0; i < 2; ++i)
#pragma unroll
        for (int dk = 0; dk < 4; ++dk)
          sacc[i][jb] = __builtin_amdgcn_mfma_f32_16x16x32_bf16(qf[i][dk], kf[dk], sacc[i][jb], 0, 0, 0);
    }

#pragma unroll
    for (int i = 0; i < 2; ++i) {
      float z[4][4], mx[4];
#pragma unroll
      for (int jb = 0; jb < 4; ++jb)
#pragma unroll
        for (int r = 0; r < 4; ++r) z[jb][r] = sacc[i][jb][r] * SCL2;
#pragma unroll
      for (int r = 0; r < 4; ++r)
        mx[r] = fmaxf(fmaxf(z[0][r], z[1][r]), fmaxf(z[2][r], z[3][r]));
#pragma unroll
      for (int d = 1; d < 16; d <<= 1)
#pragma unroll
        for (int r = 0; r < 4; ++r) mx[r] = fmaxf(mx[r], __shfl_xor(mx[r], d));
#pragma unroll
      for (int r = 0; r < 4; ++r) {
        const float mn = fmaxf(m_run[i][r], mx[r]);
        const float alpha = __builtin_amdgcn_exp2f(m_run[i][r] - mn);
        m_run[i][r] = mn;
        float srow = 0.f;
#pragma unroll
        for (int jb = 0; jb < 4; ++jb) {
          const float p = __builtin_amdgcn_exp2f(z[jb][r] - mn);
          z[jb][r] = p; srow += p;
        }
        l_run[i][r] = l_run[i][r] * alpha + srow;
#pragma unroll
        for (int db = 0; db < 8; ++db) of[i][db][r] *= alpha;
      }
#pragma unroll
      for (int jb = 0; jb < 4; ++jb)
#pragma unroll
        for (int r = 0; r < 4; ++r)
          ps[(i * 16 + lrow * 4 + r) * 72 + jb * 16 + lcol] = (bf16)z[jb][r];
    }

#pragma unroll
    for (int ss = 0; ss < 2; ++ss) {
      bf16x8 a0 = *(const bf16x8*)(ps + (0 * 16 + lcol) * 72 + ss * 32 + lrow * 8);
      bf16x8 a1 = *(const bf16x8*)(ps + (1 * 16 + lcol) * 72 + ss * 32 + lrow * 8);
#pragma unroll
      for (int db = 0; db < 8; ++db) {
        bf16x8 vf = *(const bf16x8*)(Vt + (db * 16 + lcol) * 64 + ((ss * 4 + lrow) ^ (lcol & 7)) * 8);
        of[0][db] = __builtin_amdgcn_mfma_f32_16x16x32_bf16(a0, vf, of[0][db], 0, 0, 0);
        of[1][db] = __builtin_amdgcn_mfma_f32_16x16x32_bf16(a1, vf, of[1][db], 0, 0, 0);
      }
    }
    __syncthreads();
  }
#pragma unroll
  for (int i = 0; i < 2; ++i)
#pragma unroll
    for (int r = 0; r < 4; ++r) {
      float l = l_run[i][r];
#pragma unroll
      for (int d = 1; d < 16; d <<= 1) l += __shfl_xor(l, d);
      const float inv = 1.f / l;
      const size_t rb = (size_t)(base_m + wave * 32 + i * 16 + lrow * 4 + r) * 2048 + h * 128;
#pragma unroll
      for (int db = 0; db < 8; ++db)
        obuf[rb + db * 16 + lcol] = (bf16)(of[i][db][r] * inv);
    }
}

extern "C" void kernel_launch(void* const* d_in, const int* in_sizes, int n_in,
                              void* d_out, int out_size, void* d_ws, size_t ws_size,
                              hipStream_t stream) {
  (void)in_sizes; (void)n_in; (void)out_size; (void)ws_size;
  const int*   q_qw = (const int*)d_in[0];   const float* q_sc = (const float*)d_in[1];
  const float* q_zp = (const float*)d_in[2]; const float* q_A  = (const float*)d_in[3];
  const float* q_B  = (const float*)d_in[4];
  const int*   k_qw = (const int*)d_in[5];   const float* k_sc = (const float*)d_in[6];
  const float* k_zp = (const float*)d_in[7]; const float* k_A  = (const float*)d_in[8];
  const float* k_B  = (const float*)d_in[9];
  const int*   v_qw = (const int*)d_in[10];  const float* v_sc = (const float*)d_in[11];
  const float* v_zp = (const float*)d_in[12];const float* v_A  = (const float*)d_in[13];
  const float* v_B  = (const float*)d_in[14];
  const int*   o_qw = (const int*)d_in[15];  const float* o_sc = (const float*)d_in[16];
  const float* o_zp = (const float*)d_in[17];const float* o_A  = (const float*)d_in[18];
  const float* o_B  = (const float*)d_in[19];
  const int*   g_qw = (const int*)d_in[20];  const float* g_sc = (const float*)d_in[21];
  const float* g_zp = (const float*)d_in[22];const float* g_A  = (const float*)d_in[23];
  const float* g_B  = (const float*)d_in[24];
  const int*   u_qw = (const int*)d_in[25];  const float* u_sc = (const float*)d_in[26];
  const float* u_zp = (const float*)d_in[27];const float* u_A  = (const float*)d_in[28];
  const float* u_B  = (const float*)d_in[29];
  const int*   d_qw = (const int*)d_in[30];  const float* d_sc = (const float*)d_in[31];
  const float* d_zp = (const float*)d_in[32];const float* d_A  = (const float*)d_in[33];
  const float* d_B  = (const float*)d_in[34];
  const float* x    = (const float*)d_in[35];
  const float* ln1w = (const float*)d_in[36];const float* ln1b = (const float*)d_in[37];
  const float* ln2w = (const float*)d_in[38];const float* ln2b = (const float*)d_in[39];

  // workspace arena — peak 112 MiB.  x1 lives in d_out (fp32).
  char* ws = (char*)d_ws;
  bf16* W = (bf16*)ws;                                    // 32 MiB dequant scratch (qkv/o/d)
  char* Wg8 = ws;                                         // FFN phase: int8 g-weights
  char* Wu8 = ws + (size_t)8192 * 2048;                   //            int8 u-weights
  char* p2  = ws + (size_t)32 * 1024 * 1024;              // 16 MiB region
  bf16* h   = (bf16*)p2;                                  // LN1 out (dead after qkv GEMM)
  char*  qh  = p2;                                        // FFN phase: int8 LN2 out (8.39 MB)
  float* s_m = (float*)(p2 + 8 * 1024 * 1024);            // 16 KB
  float* rs  = (float*)(p2 + 8 * 1024 * 1024 + 16384);    // 16 KB
  float* de  = (float*)(p2 + 8 * 1024 * 1024 + 32768);    // 16 KB
  bf16*  hA  = (bf16*)(p2 + 8 * 1024 * 1024 + 49152);     // 256 KB
  bf16*  B2g = (bf16*)(p2 + 8 * 1024 * 1024 + 49152 + 262144);  // 512 KB
  bf16*  B2u = B2g + (size_t)8192 * 32;                   // 512 KB
  float* wsg = (float*)((char*)(B2u + (size_t)8192 * 32));      // 32 KB
  float* wsu = wsg + 8192;                                // 32 KB
  bf16* C = (bf16*)(ws + (size_t)48 * 1024 * 1024);       // 64 MiB
  bf16* Cqk = C;                                          // [4096][4096] q|k
  bf16* VtG = C + (size_t)4096 * 4096;                    // [2*16*128][2048]
  bf16* obuf = VtG + (size_t)2 * 16 * 128 * 2048;         // [4096][2048]
  float* x1  = (float*)d_out;
  float* out = (float*)d_out;

  // 1. h = LN1(x)
  ln_kernel<<<4096, 256, 0, stream>>>(x, ln1w, ln1b, h);
  // 2. dequant W_q|W_k|W_v (6144x2048)
  dequant_kernel<<<2048, 256, 0, stream>>>(q_qw, q_sc, q_zp, q_A, q_B, W, 2048, 2048);
  dequant_kernel<<<2048, 256, 0, stream>>>(k_qw, k_sc, k_zp, k_A, k_B, W + (size_t)2048 * 2048, 2048, 2048);
  dequant_kernel<<<2048, 256, 0, stream>>>(v_qw, v_sc, v_zp, v_A, v_B, W + (size_t)4096 * 2048, 2048, 2048);
  // 3. qkv GEMM: q|k -> Cqk, v -> VtG (transposed packed stores)
  gemm_kernel<3><<<dim3(48, 32), 256, 0, stream>>>(h, W, Cqk, nullptr, nullptr, nullptr, VtG, 4096, 6144, 2048, 4096);
  // 4. attention
  attn_kernel<<<dim3(16, 16, 2), 256, 0, stream>>>(Cqk, VtG, obuf);
  // 5-6. x1 = x + o @ W_o^T
  dequant_kernel<<<2048, 256, 0, stream>>>(o_qw, o_sc, o_zp, o_A, o_B, W, 2048, 2048);
  gemm_kernel<1><<<dim3(16, 32), 256, 0, stream>>>(obuf, W, nullptr, x1, x, nullptr, nullptr, 4096, 2048, 2048, 2048);
  // 7. LN2 + int8 quantize (h region dead; reuse for qh/s_m/rs/de/hA/B2/wsum)
  ln_q_kernel<<<4096, 256, 0, stream>>>(x1, ln2w, ln2b, qh, s_m, rs, de);
  // 8. FFN LoRA/weight prep (W bf16 region dead; reuse for int8 weights)
  hA_kernel<<<1024, 256, 0, stream>>>(qh, s_m, g_A, u_A, hA);
  pack_w_kernel<<<8192, 256, 0, stream>>>(g_qw, g_sc, Wg8, wsg);
  pack_w_kernel<<<8192, 256, 0, stream>>>(u_qw, u_sc, Wu8, wsu);
  pack_b2_kernel<<<1024, 256, 0, stream>>>(g_B, u_B, B2g, B2u);
  // 9. g = dequant-epilogue(qh @ Wg8^T) -> C
  gemm_i8_kernel<0><<<dim3(64, 32), 256, 0, stream>>>(qh, Wg8, s_m, rs, de, g_sc, g_zp, wsg, hA, B2g, C, nullptr, 4096, 8192, 2048);
  // 10. ff = silu(g) * (qh @ Wu8^T dequant), in-place over C
  gemm_i8_kernel<1><<<dim3(64, 32), 256, 0, stream>>>(qh, Wu8, s_m, rs, de, u_sc, u_zp, wsu, hA, B2u, C, C, 4096, 8192, 2048);
  // 11-12. out = x1 + ff @ W_d^T (bf16 path)
  dequant_kernel<<<8192, 256, 0, stream>>>(d_qw, d_sc, d_zp, d_A, d_B, W, 2048, 8192);
  gemm_kernel<1><<<dim3(16, 32), 256, 0, stream>>>(C, W, nullptr, out, x1, nullptr, nullptr, 4096, 2048, 8192, 2048);
}